// Round 2
// baseline (369.689 us; speedup 1.0000x reference)
//
#include <hip/hip_runtime.h>
#include <stdint.h>

typedef unsigned short u16;
typedef short s8v __attribute__((ext_vector_type(8)));
typedef float f32x4 __attribute__((ext_vector_type(4)));

#define NB 2
#define NH 20
#define SEQ 2048
#define EMB 1280
#define HD 64
#define MT (NB*SEQ)      // 4096
#define N3E (3*EMB)      // 3840
// Q pre-scale: 64^-0.5 * log2(e) -> softmax runs in exp2 domain
#define QSCALE 0.18033688011112042f

__device__ __forceinline__ u16 f2bf(float f){
  unsigned u = __float_as_uint(f);
  u += 0x7fffu + ((u >> 16) & 1u);   // round-to-nearest-even
  return (u16)(u >> 16);
}

// ---------------- fp32 -> bf16 convert (float4 vectorized) ----------------
__global__ void cvt_bf16_kernel(const float* __restrict__ in, u16* __restrict__ out, int n4){
  int i = blockIdx.x*256 + threadIdx.x;
  if (i >= n4) return;
  float4 f = ((const float4* __restrict__)in)[i];
  ushort4 o;
  o.x = f2bf(f.x); o.y = f2bf(f.y); o.z = f2bf(f.z); o.w = f2bf(f.w);
  ((ushort4*)out)[i] = o;
}

// ------------- transpose+convert: in[R][C] f32 -> out[C][R] bf16 ----------
__global__ void tconv_kernel(const float* __restrict__ in, u16* __restrict__ out, int R, int C){
  __shared__ float tl[32][33];
  int c0 = blockIdx.x*32, r0 = blockIdx.y*32;
  int tx = threadIdx.x & 31, ty = threadIdx.x >> 5;   // 32x8
  #pragma unroll
  for (int i=0;i<4;i++)
    tl[ty + i*8][tx] = in[(size_t)(r0 + ty + i*8)*C + c0 + tx];
  __syncthreads();
  #pragma unroll
  for (int i=0;i<4;i++)
    out[(size_t)(c0 + ty + i*8)*R + r0 + tx] = f2bf(tl[tx][ty + i*8]);
}

// ---- swizzled global->LDS staging: rows of 128B (8 x 16B slots), XOR(row&7)
template<int NIT>
__device__ __forceinline__ void stage_swz(const u16* gsrc, int ld, u16* lds, int t){
  #pragma unroll
  for (int i=0;i<NIT;i++){
    int f = i*256 + t;
    int row = f >> 3, sl = f & 7;
    int ssl = sl ^ (row & 7);
    __builtin_amdgcn_global_load_lds(
      (const __attribute__((address_space(1))) void*)(gsrc + (size_t)row*ld + ssl*8),
      (__attribute__((address_space(3))) void*)(lds + f*8), 16, 0, 0);
  }
}

__device__ __forceinline__ s8v frag_ld(const u16* lds, int row, int ks){
  int sl = ks ^ (row & 7);
  return *(const s8v*)(lds + row*64 + sl*8);
}

// ---------------- GEMM: C[M][N] = A[M][K] @ Bt[N][K]^T + bias -------------
template<int EPI>
__global__ __launch_bounds__(256) void gemm_bt_kernel(
    const u16* __restrict__ A, const u16* __restrict__ Bt, const float* __restrict__ bias,
    float* __restrict__ Cout, int Ntot, int K,
    u16* __restrict__ qb, u16* __restrict__ kbf, u16* __restrict__ vT)
{
  __shared__ u16 As[128*64];
  __shared__ u16 Bs[128*64];
  int t = threadIdx.x;
  int lane = t & 63, w = t >> 6;
  int wr = w >> 1, wc = w & 1;
  int g = lane >> 4, c = lane & 15;
  int m0 = blockIdx.y*128, n0 = blockIdx.x*128;
  f32x4 acc[4][4] = {};
  for (int k0 = 0; k0 < K; k0 += 64){
    stage_swz<4>(A  + (size_t)m0*K + k0, K, As, t);
    stage_swz<4>(Bt + (size_t)n0*K + k0, K, Bs, t);
    __syncthreads();
    #pragma unroll
    for (int kb2=0;kb2<2;kb2++){
      s8v af[4], bfr[4];
      #pragma unroll
      for (int m=0;m<4;m++) af[m]  = frag_ld(As, wr*64 + m*16 + c, kb2*4 + g);
      #pragma unroll
      for (int n=0;n<4;n++) bfr[n] = frag_ld(Bs, wc*64 + n*16 + c, kb2*4 + g);
      #pragma unroll
      for (int m=0;m<4;m++)
        #pragma unroll
        for (int n=0;n<4;n++)
          acc[m][n] = __builtin_amdgcn_mfma_f32_16x16x32_bf16(af[m], bfr[n], acc[m][n], 0, 0, 0);
    }
    __syncthreads();
  }
  #pragma unroll
  for (int m=0;m<4;m++){
    int growb = m0 + wr*64 + m*16 + g*4;
    #pragma unroll
    for (int n=0;n<4;n++){
      int gcol = n0 + wc*64 + n*16 + c;
      float bv = bias[gcol];
      if (EPI == 1){
        #pragma unroll
        for (int r=0;r<4;r++)
          Cout[(size_t)(growb + r)*Ntot + gcol] = acc[m][n][r] + bv;
      } else {
        int which = gcol / EMB;           // 0=Q 1=K 2=V (uniform per n-tile)
        int e = gcol - which*EMB;
        int hh = e >> 6, d = e & 63;
        int bi = growb >> 11, sb = growb & 2047;
        size_t bh = (size_t)bi*NH + hh;
        if (which == 2){
          ushort4 pv;
          pv.x = f2bf(acc[m][n][0] + bv);
          pv.y = f2bf(acc[m][n][1] + bv);
          pv.z = f2bf(acc[m][n][2] + bv);
          pv.w = f2bf(acc[m][n][3] + bv);
          *(ushort4*)(vT + (bh*HD + d)*SEQ + sb) = pv;
        } else {
          u16* dst = (which == 0) ? qb : kbf;
          float scl = (which == 0) ? QSCALE : 1.0f;
          #pragma unroll
          for (int r=0;r<4;r++)
            dst[(bh*SEQ + sb + r)*HD + d] = f2bf((acc[m][n][r] + bv)*scl);
        }
      }
    }
  }
}

// ---------------- causal flash attention, barrier-free --------------------
// grid (bh=40, qpair=16); 4 independent waves, wave w owns 16 q-rows.
// K/V read direct from global (L2-resident per XCD: bh % 8 pins to XCD).
// Block does q-tiles {qp, 31-qp} -> uniform 33 k-tiles per block.
__global__ __launch_bounds__(256) void attn_kernel(
    const u16* __restrict__ qb, const u16* __restrict__ kbf, const u16* __restrict__ vT,
    u16* __restrict__ attn)
{
  __shared__ u16 Ps[4][16*72];    // per-wave P, row stride 144B
  int bh = blockIdx.x;
  int b = bh / NH, h = bh - b*NH;
  int qp = blockIdx.y;
  int t = threadIdx.x, lane = t & 63, w = t >> 6;
  int g = lane >> 4, c = lane & 15;
  u16* pw = &Ps[w][0];
  const u16* Kb = kbf + (size_t)bh*SEQ*HD;
  const u16* Vb = vT  + (size_t)bh*HD*SEQ;

  #pragma unroll 1
  for (int ph = 0; ph < 2; ph++){
    int qt = ph ? (31 - qp) : qp;
    int qwb = qt*64 + w*16;
    const u16* qrow = qb + ((size_t)bh*SEQ + qwb + c)*HD;
    s8v aq0 = *(const s8v*)(qrow + g*8);
    s8v aq1 = *(const s8v*)(qrow + 32 + g*8);
    f32x4 po[4] = {};
    float mrow[4] = {-1e30f,-1e30f,-1e30f,-1e30f};
    float lrow[4] = {0.f,0.f,0.f,0.f};

    for (int kt = 0; kt <= qt; kt++){
      int k0 = kt*64;
      // hoist V fragments (independent of softmax) for ILP
      s8v vf[2][4];
      #pragma unroll
      for (int kb2=0;kb2<2;kb2++)
        #pragma unroll
        for (int dt=0;dt<4;dt++)
          vf[kb2][dt] = *(const s8v*)(Vb + (size_t)(dt*16 + c)*SEQ + k0 + (kb2*4 + g)*8);
      // QK^T: B-fragments direct from global K
      f32x4 sc[4];
      #pragma unroll
      for (int nt=0;nt<4;nt++){
        const u16* kr = Kb + (size_t)(k0 + nt*16 + c)*HD;
        s8v b0 = *(const s8v*)(kr + g*8);
        s8v b1 = *(const s8v*)(kr + 32 + g*8);
        f32x4 z = {0.f,0.f,0.f,0.f};
        sc[nt] = __builtin_amdgcn_mfma_f32_16x16x32_bf16(aq0, b0, z,      0,0,0);
        sc[nt] = __builtin_amdgcn_mfma_f32_16x16x32_bf16(aq1, b1, sc[nt], 0,0,0);
      }
      if (kt == qt){               // causal mask, diagonal tile only
        #pragma unroll
        for (int nt=0;nt<4;nt++){
          int ka = k0 + nt*16 + c;
          #pragma unroll
          for (int r=0;r<4;r++)
            if (ka > qwb + g*4 + r) sc[nt][r] = -1e30f;
        }
      }
      // wave-parallel online softmax (exp2 domain; Q pre-scaled by 1/8*log2e)
      float mt[4];
      #pragma unroll
      for (int r=0;r<4;r++)
        mt[r] = fmaxf(fmaxf(sc[0][r], sc[1][r]), fmaxf(sc[2][r], sc[3][r]));
      #pragma unroll
      for (int off=1; off<16; off<<=1)
        #pragma unroll
        for (int r=0;r<4;r++)
          mt[r] = fmaxf(mt[r], __shfl_xor(mt[r], off));
      float alpha[4], rs[4];
      #pragma unroll
      for (int r=0;r<4;r++){
        float mn = fmaxf(mrow[r], mt[r]);
        alpha[r] = exp2f(mrow[r] - mn);
        mrow[r] = mn;
        rs[r] = 0.f;
      }
      #pragma unroll
      for (int nt=0;nt<4;nt++)
        #pragma unroll
        for (int r=0;r<4;r++){
          float pe = exp2f(sc[nt][r] - mrow[r]);
          sc[nt][r] = pe;
          rs[r] += pe;
        }
      #pragma unroll
      for (int off=1; off<16; off<<=1)
        #pragma unroll
        for (int r=0;r<4;r++)
          rs[r] += __shfl_xor(rs[r], off);
      #pragma unroll
      for (int r=0;r<4;r++)
        lrow[r] = lrow[r]*alpha[r] + rs[r];
      #pragma unroll
      for (int dt=0;dt<4;dt++)
        #pragma unroll
        for (int r=0;r<4;r++)
          po[dt][r] *= alpha[r];
      // P -> wave-private LDS (no barrier: same-wave write->read, lgkmcnt)
      #pragma unroll
      for (int nt=0;nt<4;nt++)
        #pragma unroll
        for (int r=0;r<4;r++)
          pw[(g*4 + r)*72 + nt*16 + c] = f2bf(sc[nt][r]);
      #pragma unroll
      for (int kb2=0;kb2<2;kb2++){
        s8v pa = *(const s8v*)(pw + c*72 + kb2*32 + g*8);
        #pragma unroll
        for (int dt=0;dt<4;dt++)
          po[dt] = __builtin_amdgcn_mfma_f32_16x16x32_bf16(pa, vf[kb2][dt], po[dt], 0,0,0);
      }
    }
    #pragma unroll
    for (int dt=0;dt<4;dt++){
      #pragma unroll
      for (int r=0;r<4;r++){
        int qa = qwb + g*4 + r;
        float inv = 1.0f / lrow[r];
        attn[((size_t)(b*SEQ + qa))*EMB + h*HD + dt*16 + c] = f2bf(po[dt][r] * inv);
      }
    }
  }
}

extern "C" void kernel_launch(void* const* d_in, const int* in_sizes, int n_in,
                              void* d_out, int out_size, void* d_ws, size_t ws_size,
                              hipStream_t stream) {
  const float* hs    = (const float*)d_in[0];
  const float* qkv_w = (const float*)d_in[1];
  const float* qkv_b = (const float*)d_in[2];
  const float* out_w = (const float*)d_in[3];
  const float* out_b = (const float*)d_in[4];
  float* out = (float*)d_out;

  char* p = (char*)d_ws;
  u16* xb    = (u16*)p; p += (size_t)MT*EMB*2;
  u16* wqkvT = (u16*)p; p += (size_t)N3E*EMB*2;
  u16* woT   = (u16*)p; p += (size_t)EMB*EMB*2;
  u16* qbuf  = (u16*)p; p += (size_t)NB*NH*SEQ*HD*2;
  u16* kbuf  = (u16*)p; p += (size_t)NB*NH*SEQ*HD*2;
  u16* vTb   = (u16*)p; p += (size_t)NB*NH*SEQ*HD*2;
  u16* attnb = (u16*)p; p += (size_t)MT*EMB*2;

  cvt_bf16_kernel<<<(MT*EMB/4 + 255)/256, 256, 0, stream>>>(hs, xb, MT*EMB/4);
  tconv_kernel<<<dim3(N3E/32, EMB/32), 256, 0, stream>>>(qkv_w, wqkvT, EMB, N3E);
  tconv_kernel<<<dim3(EMB/32, EMB/32), 256, 0, stream>>>(out_w, woT, EMB, EMB);
  gemm_bt_kernel<0><<<dim3(N3E/128, MT/128), 256, 0, stream>>>(
      xb, wqkvT, qkv_b, nullptr, N3E, EMB, qbuf, kbuf, vTb);
  attn_kernel<<<dim3(40, 16), 256, 0, stream>>>(qbuf, kbuf, vTb, attnb);
  gemm_bt_kernel<1><<<dim3(EMB/128, MT/128), 256, 0, stream>>>(
      attnb, woT, out_b, out, EMB, EMB, nullptr, nullptr, nullptr);
}

// Round 3
// 351.770 us; speedup vs baseline: 1.0509x; 1.0509x over previous
//
#include <hip/hip_runtime.h>
#include <stdint.h>

typedef unsigned short u16;
typedef short s8v __attribute__((ext_vector_type(8)));
typedef float f32x4 __attribute__((ext_vector_type(4)));

#define NB 2
#define NH 20
#define SEQ 2048
#define EMB 1280
#define HD 64
#define MT (NB*SEQ)      // 4096
#define N3E (3*EMB)      // 3840
// Q pre-scale: 64^-0.5 * log2(e) -> softmax runs in exp2 domain
#define QSCALE 0.18033688011112042f

__device__ __forceinline__ u16 f2bf(float f){
  unsigned u = __float_as_uint(f);
  u += 0x7fffu + ((u >> 16) & 1u);   // round-to-nearest-even
  return (u16)(u >> 16);
}

// ---------------- fp32 -> bf16 convert (float4 vectorized) ----------------
__global__ void cvt_bf16_kernel(const float* __restrict__ in, u16* __restrict__ out, int n4){
  int i = blockIdx.x*256 + threadIdx.x;
  if (i >= n4) return;
  float4 f = ((const float4* __restrict__)in)[i];
  ushort4 o;
  o.x = f2bf(f.x); o.y = f2bf(f.y); o.z = f2bf(f.z); o.w = f2bf(f.w);
  ((ushort4*)out)[i] = o;
}

// ------------- transpose+convert: in[R][C] f32 -> out[C][R] bf16 ----------
__global__ void tconv_kernel(const float* __restrict__ in, u16* __restrict__ out, int R, int C){
  __shared__ float tl[32][33];
  int c0 = blockIdx.x*32, r0 = blockIdx.y*32;
  int tx = threadIdx.x & 31, ty = threadIdx.x >> 5;   // 32x8
  #pragma unroll
  for (int i=0;i<4;i++)
    tl[ty + i*8][tx] = in[(size_t)(r0 + ty + i*8)*C + c0 + tx];
  __syncthreads();
  #pragma unroll
  for (int i=0;i<4;i++)
    out[(size_t)(c0 + ty + i*8)*R + r0 + tx] = f2bf(tl[tx][ty + i*8]);
}

// ---- swizzled global->LDS staging: rows of 128B (8 x 16B slots), XOR(row&7)
template<int NIT>
__device__ __forceinline__ void stage_swz(const u16* gsrc, int ld, u16* lds, int t){
  #pragma unroll
  for (int i=0;i<NIT;i++){
    int f = i*256 + t;
    int row = f >> 3, sl = f & 7;
    int ssl = sl ^ (row & 7);
    __builtin_amdgcn_global_load_lds(
      (const __attribute__((address_space(1))) void*)(gsrc + (size_t)row*ld + ssl*8),
      (__attribute__((address_space(3))) void*)(lds + f*8), 16, 0, 0);
  }
}

__device__ __forceinline__ s8v frag_ld(const u16* lds, int row, int ks){
  int sl = ks ^ (row & 7);
  return *(const s8v*)(lds + row*64 + sl*8);
}

// ---------------- GEMM: C[M][N] = A[M][K] @ Bt[N][K]^T + bias -------------
template<int EPI>
__global__ __launch_bounds__(256) void gemm_bt_kernel(
    const u16* __restrict__ A, const u16* __restrict__ Bt, const float* __restrict__ bias,
    float* __restrict__ Cout, int Ntot, int K,
    u16* __restrict__ qb, u16* __restrict__ kbf, u16* __restrict__ vT)
{
  __shared__ u16 As[128*64];
  __shared__ u16 Bs[128*64];
  int t = threadIdx.x;
  int lane = t & 63, w = t >> 6;
  int wr = w >> 1, wc = w & 1;
  int g = lane >> 4, c = lane & 15;
  int m0 = blockIdx.y*128, n0 = blockIdx.x*128;
  f32x4 acc[4][4] = {};
  for (int k0 = 0; k0 < K; k0 += 64){
    stage_swz<4>(A  + (size_t)m0*K + k0, K, As, t);
    stage_swz<4>(Bt + (size_t)n0*K + k0, K, Bs, t);
    __syncthreads();
    #pragma unroll
    for (int kb2=0;kb2<2;kb2++){
      s8v af[4], bfr[4];
      #pragma unroll
      for (int m=0;m<4;m++) af[m]  = frag_ld(As, wr*64 + m*16 + c, kb2*4 + g);
      #pragma unroll
      for (int n=0;n<4;n++) bfr[n] = frag_ld(Bs, wc*64 + n*16 + c, kb2*4 + g);
      #pragma unroll
      for (int m=0;m<4;m++)
        #pragma unroll
        for (int n=0;n<4;n++)
          acc[m][n] = __builtin_amdgcn_mfma_f32_16x16x32_bf16(af[m], bfr[n], acc[m][n], 0, 0, 0);
    }
    __syncthreads();
  }
  #pragma unroll
  for (int m=0;m<4;m++){
    int growb = m0 + wr*64 + m*16 + g*4;
    #pragma unroll
    for (int n=0;n<4;n++){
      int gcol = n0 + wc*64 + n*16 + c;
      float bv = bias[gcol];
      if (EPI == 1){
        #pragma unroll
        for (int r=0;r<4;r++)
          Cout[(size_t)(growb + r)*Ntot + gcol] = acc[m][n][r] + bv;
      } else {
        int which = gcol / EMB;           // 0=Q 1=K 2=V (uniform per n-tile)
        int e = gcol - which*EMB;
        int hh = e >> 6, d = e & 63;
        int bi = growb >> 11, sb = growb & 2047;
        size_t bh = (size_t)bi*NH + hh;
        if (which == 2){
          ushort4 pv;
          pv.x = f2bf(acc[m][n][0] + bv);
          pv.y = f2bf(acc[m][n][1] + bv);
          pv.z = f2bf(acc[m][n][2] + bv);
          pv.w = f2bf(acc[m][n][3] + bv);
          *(ushort4*)(vT + (bh*HD + d)*SEQ + sb) = pv;
        } else {
          u16* dst = (which == 0) ? qb : kbf;
          float scl = (which == 0) ? QSCALE : 1.0f;
          #pragma unroll
          for (int r=0;r<4;r++)
            dst[(bh*SEQ + sb + r)*HD + d] = f2bf((acc[m][n][r] + bv)*scl);
        }
      }
    }
  }
}

// ---------------- causal flash attention, pipelined + swapped QK^T --------
// grid (bh=40, 32); qt = 31-by (heavy tiles dispatch first). 4 independent
// waves own 16 q-rows each. Swapped mfma(K,Q) -> lane owns q-row (lane&15):
// softmax reduce = in-lane 15 fmax + 2 shfl hops. K prefetched 1 tile ahead.
__global__ __launch_bounds__(256) void attn_kernel(
    const u16* __restrict__ qb, const u16* __restrict__ kbf, const u16* __restrict__ vT,
    u16* __restrict__ attn)
{
  __shared__ u16 Ps[4][16*72];    // per-wave P[q=c][k], row stride 144B
  int bh = blockIdx.x;
  int b = bh / NH, h = bh - b*NH;
  int qt = 31 - blockIdx.y;
  int t = threadIdx.x, lane = t & 63, w = t >> 6;
  int g = lane >> 4, c = lane & 15;
  u16* pw = &Ps[w][0];
  const u16* Kb = kbf + (size_t)bh*SEQ*HD;
  const u16* Vb = vT  + (size_t)bh*HD*SEQ;

  int qwb = qt*64 + w*16;
  const u16* qrow = qb + ((size_t)bh*SEQ + qwb + c)*HD;
  s8v aq0 = *(const s8v*)(qrow + g*8);
  s8v aq1 = *(const s8v*)(qrow + 32 + g*8);
  f32x4 po[4] = {};
  float mrow = -1e30f, lrow = 0.f;      // per-lane: row q = c

  // preload K tile 0 fragments (row = c within tile)
  s8v ka[8];
  #pragma unroll
  for (int nt=0;nt<4;nt++){
    const u16* kr = Kb + (size_t)(nt*16 + c)*HD;
    ka[nt*2]   = *(const s8v*)(kr + g*8);
    ka[nt*2+1] = *(const s8v*)(kr + 32 + g*8);
  }

  for (int kt = 0; kt <= qt; ++kt){
    int k0 = kt*64;
    // issue V(t) loads early (consumed after softmax, ~400cy coverage)
    s8v vv[8];
    #pragma unroll
    for (int kb2=0;kb2<2;kb2++)
      #pragma unroll
      for (int dt=0;dt<4;dt++)
        vv[kb2*4+dt] = *(const s8v*)(Vb + (size_t)(dt*16 + c)*SEQ + k0 + kb2*32 + g*8);
    // QK^T swapped: D = K·Q^T -> lane (g,c) holds S[q=c][k=k0+nt*16+g*4+r]
    f32x4 sc[4];
    #pragma unroll
    for (int nt=0;nt<4;nt++){
      f32x4 z = {0.f,0.f,0.f,0.f};
      sc[nt] = __builtin_amdgcn_mfma_f32_16x16x32_bf16(ka[nt*2],   aq0, z,      0,0,0);
      sc[nt] = __builtin_amdgcn_mfma_f32_16x16x32_bf16(ka[nt*2+1], aq1, sc[nt], 0,0,0);
    }
    // prefetch K(t+1) into same regs (consumed next iter, ~500cy coverage)
    if (kt < qt){
      const u16* krn = Kb + (size_t)(k0 + 64 + c)*HD;
      #pragma unroll
      for (int nt=0;nt<4;nt++){
        ka[nt*2]   = *(const s8v*)(krn + nt*16*HD + g*8);
        ka[nt*2+1] = *(const s8v*)(krn + nt*16*HD + 32 + g*8);
      }
    }
    // causal mask (diagonal tile only): k index = k0+nt*16+g*4+r, q = qwb+c
    if (kt == qt){
      #pragma unroll
      for (int nt=0;nt<4;nt++){
        int kg = k0 + nt*16 + g*4;
        #pragma unroll
        for (int r=0;r<4;r++)
          if (kg + r > qwb + c) sc[nt][r] = -1e30f;
      }
    }
    // row max: 15 in-lane fmax + 2 shfl hops (row spread over 4 g-lanes)
    float mt = fmaxf(fmaxf(sc[0][0],sc[0][1]), fmaxf(sc[0][2],sc[0][3]));
    #pragma unroll
    for (int nt=1;nt<4;nt++)
      mt = fmaxf(mt, fmaxf(fmaxf(sc[nt][0],sc[nt][1]), fmaxf(sc[nt][2],sc[nt][3])));
    mt = fmaxf(mt, __shfl_xor(mt, 16));
    mt = fmaxf(mt, __shfl_xor(mt, 32));
    float mn = fmaxf(mrow, mt);
    float alpha = exp2f(mrow - mn);
    mrow = mn;
    float rs = 0.f;
    #pragma unroll
    for (int nt=0;nt<4;nt++)
      #pragma unroll
      for (int r=0;r<4;r++){
        float pe = exp2f(sc[nt][r] - mn);
        sc[nt][r] = pe;
        rs += pe;
      }
    rs += __shfl_xor(rs, 16);
    rs += __shfl_xor(rs, 32);
    lrow = lrow*alpha + rs;
    // broadcast alpha from row-owner lanes (q=c) to po layout (q=g*4+r)
    float alB[4];
    #pragma unroll
    for (int r=0;r<4;r++)
      alB[r] = __shfl(alpha, (lane & 48) | (g*4 + r));
    #pragma unroll
    for (int dt=0;dt<4;dt++)
      #pragma unroll
      for (int r=0;r<4;r++)
        po[dt][r] *= alB[r];
    // P -> wave-private LDS: 4x ds_write_b64 (k-chunks are lane-contiguous)
    #pragma unroll
    for (int nt=0;nt<4;nt++){
      ushort4 pk;
      pk.x = f2bf(sc[nt][0]); pk.y = f2bf(sc[nt][1]);
      pk.z = f2bf(sc[nt][2]); pk.w = f2bf(sc[nt][3]);
      *(ushort4*)(pw + c*72 + nt*16 + g*4) = pk;
    }
    // PV: A = P[q=c][k=kb2*32+g*8..], B = V^T fragments
    #pragma unroll
    for (int kb2=0;kb2<2;kb2++){
      s8v pa = *(const s8v*)(pw + c*72 + kb2*32 + g*8);
      #pragma unroll
      for (int dt=0;dt<4;dt++)
        po[dt] = __builtin_amdgcn_mfma_f32_16x16x32_bf16(pa, vv[kb2*4+dt], po[dt], 0,0,0);
    }
  }
  // epilogue: broadcast 1/l from row-owner lanes, write O
  float inv = 1.0f / lrow;
  float invB[4];
  #pragma unroll
  for (int r=0;r<4;r++)
    invB[r] = __shfl(inv, (lane & 48) | (g*4 + r));
  #pragma unroll
  for (int dt=0;dt<4;dt++){
    #pragma unroll
    for (int r=0;r<4;r++){
      int qa = qwb + g*4 + r;
      attn[((size_t)(b*SEQ + qa))*EMB + h*HD + dt*16 + c] = f2bf(po[dt][r] * invB[r]);
    }
  }
}

extern "C" void kernel_launch(void* const* d_in, const int* in_sizes, int n_in,
                              void* d_out, int out_size, void* d_ws, size_t ws_size,
                              hipStream_t stream) {
  const float* hs    = (const float*)d_in[0];
  const float* qkv_w = (const float*)d_in[1];
  const float* qkv_b = (const float*)d_in[2];
  const float* out_w = (const float*)d_in[3];
  const float* out_b = (const float*)d_in[4];
  float* out = (float*)d_out;

  char* p = (char*)d_ws;
  u16* xb    = (u16*)p; p += (size_t)MT*EMB*2;
  u16* wqkvT = (u16*)p; p += (size_t)N3E*EMB*2;
  u16* woT   = (u16*)p; p += (size_t)EMB*EMB*2;
  u16* qbuf  = (u16*)p; p += (size_t)NB*NH*SEQ*HD*2;
  u16* kbuf  = (u16*)p; p += (size_t)NB*NH*SEQ*HD*2;
  u16* vTb   = (u16*)p; p += (size_t)NB*NH*SEQ*HD*2;
  u16* attnb = (u16*)p; p += (size_t)MT*EMB*2;

  cvt_bf16_kernel<<<(MT*EMB/4 + 255)/256, 256, 0, stream>>>(hs, xb, MT*EMB/4);
  tconv_kernel<<<dim3(N3E/32, EMB/32), 256, 0, stream>>>(qkv_w, wqkvT, EMB, N3E);
  tconv_kernel<<<dim3(EMB/32, EMB/32), 256, 0, stream>>>(out_w, woT, EMB, EMB);
  gemm_bt_kernel<0><<<dim3(N3E/128, MT/128), 256, 0, stream>>>(
      xb, wqkvT, qkv_b, nullptr, N3E, EMB, qbuf, kbuf, vTb);
  attn_kernel<<<dim3(40, 32), 256, 0, stream>>>(qbuf, kbuf, vTb, attnb);
  gemm_bt_kernel<1><<<dim3(EMB/128, MT/128), 256, 0, stream>>>(
      attnb, woT, out_b, out, EMB, EMB, nullptr, nullptr, nullptr);
}

// Round 4
// 259.532 us; speedup vs baseline: 1.4244x; 1.3554x over previous
//
#include <hip/hip_runtime.h>
#include <stdint.h>

typedef unsigned short u16;
typedef short s8v __attribute__((ext_vector_type(8)));
typedef float f32x4 __attribute__((ext_vector_type(4)));

#define NB 2
#define NH 20
#define SEQ 2048
#define EMB 1280
#define HD 64
#define MT (NB*SEQ)      // 4096
#define N3E (3*EMB)      // 3840
// Q pre-scale: 64^-0.5 * log2(e) -> softmax runs in exp2 domain
#define QSCALE 0.18033688011112042f

__device__ __forceinline__ u16 f2bf(float f){
  unsigned u = __float_as_uint(f);
  u += 0x7fffu + ((u >> 16) & 1u);   // round-to-nearest-even
  return (u16)(u >> 16);
}

// ---------------- fp32 -> bf16 convert (float4 vectorized) ----------------
__global__ void cvt_bf16_kernel(const float* __restrict__ in, u16* __restrict__ out, int n4){
  int i = blockIdx.x*256 + threadIdx.x;
  if (i >= n4) return;
  float4 f = ((const float4* __restrict__)in)[i];
  ushort4 o;
  o.x = f2bf(f.x); o.y = f2bf(f.y); o.z = f2bf(f.z); o.w = f2bf(f.w);
  ((ushort4*)out)[i] = o;
}

// ------------- transpose+convert: in[R][C] f32 -> out[C][R] bf16 ----------
__global__ void tconv_kernel(const float* __restrict__ in, u16* __restrict__ out, int R, int C){
  __shared__ float tl[32][33];
  int c0 = blockIdx.x*32, r0 = blockIdx.y*32;
  int tx = threadIdx.x & 31, ty = threadIdx.x >> 5;   // 32x8
  #pragma unroll
  for (int i=0;i<4;i++)
    tl[ty + i*8][tx] = in[(size_t)(r0 + ty + i*8)*C + c0 + tx];
  __syncthreads();
  #pragma unroll
  for (int i=0;i<4;i++)
    out[(size_t)(c0 + ty + i*8)*R + r0 + tx] = f2bf(tl[tx][ty + i*8]);
}

// ---- swizzled global->LDS staging: rows of 128B (8 x 16B slots), XOR(row&7)
template<int NIT>
__device__ __forceinline__ void stage_swz(const u16* gsrc, int ld, u16* lds, int t){
  #pragma unroll
  for (int i=0;i<NIT;i++){
    int f = i*256 + t;
    int row = f >> 3, sl = f & 7;
    int ssl = sl ^ (row & 7);
    __builtin_amdgcn_global_load_lds(
      (const __attribute__((address_space(1))) void*)(gsrc + (size_t)row*ld + ssl*8),
      (__attribute__((address_space(3))) void*)(lds + f*8), 16, 0, 0);
  }
}

__device__ __forceinline__ s8v frag_ld(const u16* lds, int row, int ks){
  int sl = ks ^ (row & 7);
  return *(const s8v*)(lds + row*64 + sl*8);
}

// ---------------- GEMM: C[M][N] = A[M][K] @ Bt[N][K]^T + bias -------------
template<int EPI>
__global__ __launch_bounds__(256) void gemm_bt_kernel(
    const u16* __restrict__ A, const u16* __restrict__ Bt, const float* __restrict__ bias,
    float* __restrict__ Cout, int Ntot, int K,
    u16* __restrict__ qb, u16* __restrict__ kbf, u16* __restrict__ vT)
{
  __shared__ u16 As[128*64];
  __shared__ u16 Bs[128*64];
  int t = threadIdx.x;
  int lane = t & 63, w = t >> 6;
  int wr = w >> 1, wc = w & 1;
  int g = lane >> 4, c = lane & 15;
  int m0 = blockIdx.y*128, n0 = blockIdx.x*128;
  f32x4 acc[4][4] = {};
  for (int k0 = 0; k0 < K; k0 += 64){
    stage_swz<4>(A  + (size_t)m0*K + k0, K, As, t);
    stage_swz<4>(Bt + (size_t)n0*K + k0, K, Bs, t);
    __syncthreads();
    #pragma unroll
    for (int kb2=0;kb2<2;kb2++){
      s8v af[4], bfr[4];
      #pragma unroll
      for (int m=0;m<4;m++) af[m]  = frag_ld(As, wr*64 + m*16 + c, kb2*4 + g);
      #pragma unroll
      for (int n=0;n<4;n++) bfr[n] = frag_ld(Bs, wc*64 + n*16 + c, kb2*4 + g);
      #pragma unroll
      for (int m=0;m<4;m++)
        #pragma unroll
        for (int n=0;n<4;n++)
          acc[m][n] = __builtin_amdgcn_mfma_f32_16x16x32_bf16(af[m], bfr[n], acc[m][n], 0, 0, 0);
    }
    __syncthreads();
  }
  #pragma unroll
  for (int m=0;m<4;m++){
    int growb = m0 + wr*64 + m*16 + g*4;
    #pragma unroll
    for (int n=0;n<4;n++){
      int gcol = n0 + wc*64 + n*16 + c;
      float bv = bias[gcol];
      if (EPI == 1){
        #pragma unroll
        for (int r=0;r<4;r++)
          Cout[(size_t)(growb + r)*Ntot + gcol] = acc[m][n][r] + bv;
      } else {
        int which = gcol / EMB;           // 0=Q 1=K 2=V (uniform per n-tile)
        int e = gcol - which*EMB;
        int hh = e >> 6, d = e & 63;
        int bi = growb >> 11, sb = growb & 2047;
        size_t bh = (size_t)bi*NH + hh;
        if (which == 2){
          ushort4 pv;
          pv.x = f2bf(acc[m][n][0] + bv);
          pv.y = f2bf(acc[m][n][1] + bv);
          pv.z = f2bf(acc[m][n][2] + bv);
          pv.w = f2bf(acc[m][n][3] + bv);
          *(ushort4*)(vT + (bh*HD + d)*SEQ + sb) = pv;
        } else {
          u16* dst = (which == 0) ? qb : kbf;
          float scl = (which == 0) ? QSCALE : 1.0f;
          #pragma unroll
          for (int r=0;r<4;r++)
            dst[(bh*SEQ + sb + r)*HD + d] = f2bf((acc[m][n][r] + bv)*scl);
        }
      }
    }
  }
}

// ------- causal flash attention: LDS double-buffer + counted vmcnt --------
// grid (bh=40, 32); qt = 31-by (heavy first). 4 waves own 16 q-rows each.
// K,V^T tiles staged via global_load_lds (coalesced, shared by all waves),
// double-buffered; tile t+1's 4 DMA loads stay in flight under tile t's
// compute (s_waitcnt vmcnt(4), never 0 mid-loop). Swapped QK^T keeps the
// softmax row in-lane (q = lane&15).
__global__ __launch_bounds__(256) void attn_kernel(
    const u16* __restrict__ qb, const u16* __restrict__ kbf, const u16* __restrict__ vT,
    u16* __restrict__ attn)
{
  __shared__ u16 Kls[2][64*64];   // K tile [s][d], swizzled
  __shared__ u16 Vls[2][64*64];   // V^T tile [d][s], swizzled
  __shared__ u16 Ps[4][16*72];    // per-wave P[q=c][k], row stride 144B
  int bh = blockIdx.x;
  int b = bh / NH, h = bh - b*NH;
  int qt = 31 - blockIdx.y;
  int t = threadIdx.x, lane = t & 63, w = t >> 6;
  int g = lane >> 4, c = lane & 15;
  u16* pw = &Ps[w][0];
  const u16* Kb = kbf + (size_t)bh*SEQ*HD;
  const u16* Vb = vT  + (size_t)bh*HD*SEQ;

  int qwb = qt*64 + w*16;
  const u16* qrow = qb + ((size_t)bh*SEQ + qwb + c)*HD;
  s8v aq0 = *(const s8v*)(qrow + g*8);
  s8v aq1 = *(const s8v*)(qrow + 32 + g*8);
  f32x4 po[4] = {};
  float mrow = -1e30f, lrow = 0.f;      // per-lane: row q = c

  // prologue: stage tile 0 into buffer 0 (2 K + 2 V loads per thread)
  stage_swz<2>(Kb, HD, Kls[0], t);
  stage_swz<2>(Vb, SEQ, Vls[0], t);

  for (int kt = 0; kt <= qt; ++kt){
    int cur = kt & 1;
    const u16* Ks = Kls[cur];
    const u16* Vs = Vls[cur];
    if (kt < qt){
      int k1 = (kt + 1)*64;
      stage_swz<2>(Kb + (size_t)k1*HD, HD,  Kls[cur^1], t);
      stage_swz<2>(Vb + k1,            SEQ, Vls[cur^1], t);
      asm volatile("s_waitcnt vmcnt(4)" ::: "memory");   // tile t landed; t+1 in flight
    } else {
      asm volatile("s_waitcnt vmcnt(0)" ::: "memory");
    }
    __builtin_amdgcn_s_barrier();
    __builtin_amdgcn_sched_barrier(0);

    int k0 = kt*64;
    // V^T fragments early (consumed at PV; latency hides under QK^T+softmax)
    s8v vv[8];
    #pragma unroll
    for (int kb2=0;kb2<2;kb2++)
      #pragma unroll
      for (int dt=0;dt<4;dt++)
        vv[kb2*4+dt] = frag_ld(Vs, dt*16 + c, kb2*4 + g);
    // QK^T swapped: D = K·Q^T -> lane (c,g) holds S[q=c][k=k0+nt*16+g*4+r]
    f32x4 sc[4];
    #pragma unroll
    for (int nt=0;nt<4;nt++){
      s8v k0f = frag_ld(Ks, nt*16 + c, g);
      s8v k1f = frag_ld(Ks, nt*16 + c, 4 + g);
      f32x4 z = {0.f,0.f,0.f,0.f};
      sc[nt] = __builtin_amdgcn_mfma_f32_16x16x32_bf16(k0f, aq0, z,      0,0,0);
      sc[nt] = __builtin_amdgcn_mfma_f32_16x16x32_bf16(k1f, aq1, sc[nt], 0,0,0);
    }
    // causal mask (diagonal tile only): k = k0+nt*16+g*4+r, q = qwb+c
    if (kt == qt){
      #pragma unroll
      for (int nt=0;nt<4;nt++){
        int kg = k0 + nt*16 + g*4;
        #pragma unroll
        for (int r=0;r<4;r++)
          if (kg + r > qwb + c) sc[nt][r] = -1e30f;
      }
    }
    // row max: in-lane fmax tree + 2 shfl hops
    float mt = fmaxf(fmaxf(sc[0][0],sc[0][1]), fmaxf(sc[0][2],sc[0][3]));
    #pragma unroll
    for (int nt=1;nt<4;nt++)
      mt = fmaxf(mt, fmaxf(fmaxf(sc[nt][0],sc[nt][1]), fmaxf(sc[nt][2],sc[nt][3])));
    mt = fmaxf(mt, __shfl_xor(mt, 16));
    mt = fmaxf(mt, __shfl_xor(mt, 32));
    float mn = fmaxf(mrow, mt);
    float alpha = exp2f(mrow - mn);
    mrow = mn;
    float rs = 0.f;
    #pragma unroll
    for (int nt=0;nt<4;nt++)
      #pragma unroll
      for (int r=0;r<4;r++){
        float pe = exp2f(sc[nt][r] - mn);
        sc[nt][r] = pe;
        rs += pe;
      }
    rs += __shfl_xor(rs, 16);
    rs += __shfl_xor(rs, 32);
    lrow = lrow*alpha + rs;
    // broadcast alpha from row-owner lanes (q=c) to po layout (q=g*4+r)
    float alB[4];
    #pragma unroll
    for (int r=0;r<4;r++)
      alB[r] = __shfl(alpha, (lane & 48) | (g*4 + r));
    #pragma unroll
    for (int dt=0;dt<4;dt++)
      #pragma unroll
      for (int r=0;r<4;r++)
        po[dt][r] *= alB[r];
    // P -> wave-private LDS (redistribute k within 4-lane group), then PV
    #pragma unroll
    for (int nt=0;nt<4;nt++){
      ushort4 pk;
      pk.x = f2bf(sc[nt][0]); pk.y = f2bf(sc[nt][1]);
      pk.z = f2bf(sc[nt][2]); pk.w = f2bf(sc[nt][3]);
      *(ushort4*)(pw + c*72 + nt*16 + g*4) = pk;
    }
    #pragma unroll
    for (int kb2=0;kb2<2;kb2++){
      s8v pa = *(const s8v*)(pw + c*72 + kb2*32 + g*8);
      #pragma unroll
      for (int dt=0;dt<4;dt++)
        po[dt] = __builtin_amdgcn_mfma_f32_16x16x32_bf16(pa, vv[kb2*4+dt], po[dt], 0,0,0);
    }
    // all LDS reads retired before next iter's DMA may overwrite this buffer
    asm volatile("s_waitcnt lgkmcnt(0)" ::: "memory");
    __builtin_amdgcn_s_barrier();
  }
  // epilogue: broadcast 1/l from row-owner lanes, write O
  float inv = 1.0f / lrow;
  float invB[4];
  #pragma unroll
  for (int r=0;r<4;r++)
    invB[r] = __shfl(inv, (lane & 48) | (g*4 + r));
  #pragma unroll
  for (int dt=0;dt<4;dt++){
    #pragma unroll
    for (int r=0;r<4;r++){
      int qa = qwb + g*4 + r;
      attn[((size_t)(b*SEQ + qa))*EMB + h*HD + dt*16 + c] = f2bf(po[dt][r] * invB[r]);
    }
  }
}

extern "C" void kernel_launch(void* const* d_in, const int* in_sizes, int n_in,
                              void* d_out, int out_size, void* d_ws, size_t ws_size,
                              hipStream_t stream) {
  const float* hs    = (const float*)d_in[0];
  const float* qkv_w = (const float*)d_in[1];
  const float* qkv_b = (const float*)d_in[2];
  const float* out_w = (const float*)d_in[3];
  const float* out_b = (const float*)d_in[4];
  float* out = (float*)d_out;

  char* p = (char*)d_ws;
  u16* xb    = (u16*)p; p += (size_t)MT*EMB*2;
  u16* wqkvT = (u16*)p; p += (size_t)N3E*EMB*2;
  u16* woT   = (u16*)p; p += (size_t)EMB*EMB*2;
  u16* qbuf  = (u16*)p; p += (size_t)NB*NH*SEQ*HD*2;
  u16* kbuf  = (u16*)p; p += (size_t)NB*NH*SEQ*HD*2;
  u16* vTb   = (u16*)p; p += (size_t)NB*NH*SEQ*HD*2;
  u16* attnb = (u16*)p; p += (size_t)MT*EMB*2;

  cvt_bf16_kernel<<<(MT*EMB/4 + 255)/256, 256, 0, stream>>>(hs, xb, MT*EMB/4);
  tconv_kernel<<<dim3(N3E/32, EMB/32), 256, 0, stream>>>(qkv_w, wqkvT, EMB, N3E);
  tconv_kernel<<<dim3(EMB/32, EMB/32), 256, 0, stream>>>(out_w, woT, EMB, EMB);
  gemm_bt_kernel<0><<<dim3(N3E/128, MT/128), 256, 0, stream>>>(
      xb, wqkvT, qkv_b, nullptr, N3E, EMB, qbuf, kbuf, vTb);
  attn_kernel<<<dim3(40, 32), 256, 0, stream>>>(qbuf, kbuf, vTb, attnb);
  gemm_bt_kernel<1><<<dim3(EMB/128, MT/128), 256, 0, stream>>>(
      attnb, woT, out_b, out, EMB, EMB, nullptr, nullptr, nullptr);
}

// Round 5
// 254.282 us; speedup vs baseline: 1.4539x; 1.0206x over previous
//
#include <hip/hip_runtime.h>
#include <stdint.h>

typedef unsigned short u16;
typedef short s8v __attribute__((ext_vector_type(8)));
typedef float f32x4 __attribute__((ext_vector_type(4)));

#define NB 2
#define NH 20
#define SEQ 2048
#define EMB 1280
#define HD 64
#define MT (NB*SEQ)      // 4096
#define N3E (3*EMB)      // 3840
// Q pre-scale: 64^-0.5 * log2(e) -> softmax runs in exp2 domain
#define QSCALE 0.18033688011112042f

__device__ __forceinline__ u16 f2bf(float f){
  unsigned u = __float_as_uint(f);
  u += 0x7fffu + ((u >> 16) & 1u);   // round-to-nearest-even
  return (u16)(u >> 16);
}

// ---- merged prep: fp32->bf16 convert of X + two transpose-converts -------
// blocks [0,5120): cvt X; [5120,9920): qkv_w^T; [9920,11520): out_w^T
__global__ __launch_bounds__(256) void prep_kernel(
    const float* __restrict__ hs, const float* __restrict__ qkv_w,
    const float* __restrict__ out_w,
    u16* __restrict__ xb, u16* __restrict__ wqkvT, u16* __restrict__ woT)
{
  __shared__ float tl[32][33];
  int blk = blockIdx.x;
  if (blk < 5120){
    int i = blk*256 + threadIdx.x;     // n4 = MT*EMB/4 = 1310720 = 5120*256
    float4 f = ((const float4* __restrict__)hs)[i];
    ushort4 o;
    o.x = f2bf(f.x); o.y = f2bf(f.y); o.z = f2bf(f.z); o.w = f2bf(f.w);
    ((ushort4*)xb)[i] = o;
    return;
  }
  const float* in; u16* out; int R, C, bx, by;
  if (blk < 9920){
    int b2 = blk - 5120; bx = b2 % 120; by = b2 / 120;
    in = qkv_w; out = wqkvT; R = EMB; C = N3E;
  } else {
    int b2 = blk - 9920; bx = b2 % 40; by = b2 / 40;
    in = out_w; out = woT; R = EMB; C = EMB;
  }
  int c0 = bx*32, r0 = by*32;
  int tx = threadIdx.x & 31, ty = threadIdx.x >> 5;   // 32x8
  #pragma unroll
  for (int i=0;i<4;i++)
    tl[ty + i*8][tx] = in[(size_t)(r0 + ty + i*8)*C + c0 + tx];
  __syncthreads();
  #pragma unroll
  for (int i=0;i<4;i++)
    out[(size_t)(c0 + ty + i*8)*R + r0 + tx] = f2bf(tl[tx][ty + i*8]);
}

// ---- swizzled global->LDS staging: rows of 128B (8 x 16B slots), XOR(row&7)
template<int NIT>
__device__ __forceinline__ void stage_swz(const u16* gsrc, int ld, u16* lds, int t){
  #pragma unroll
  for (int i=0;i<NIT;i++){
    int f = i*256 + t;
    int row = f >> 3, sl = f & 7;
    int ssl = sl ^ (row & 7);
    __builtin_amdgcn_global_load_lds(
      (const __attribute__((address_space(1))) void*)(gsrc + (size_t)row*ld + ssl*8),
      (__attribute__((address_space(3))) void*)(lds + f*8), 16, 0, 0);
  }
}

__device__ __forceinline__ s8v frag_ld(const u16* lds, int row, int ks){
  int sl = ks ^ (row & 7);
  return *(const s8v*)(lds + row*64 + sl*8);
}

// ---------------- GEMM: C[M][N] = A[M][K] @ Bt[N][K]^T + bias -------------
template<int EPI>
__global__ __launch_bounds__(256) void gemm_bt_kernel(
    const u16* __restrict__ A, const u16* __restrict__ Bt, const float* __restrict__ bias,
    float* __restrict__ Cout, int Ntot, int K,
    u16* __restrict__ qb, u16* __restrict__ kbf, u16* __restrict__ vT)
{
  __shared__ u16 As[128*64];
  __shared__ u16 Bs[128*64];
  int t = threadIdx.x;
  int lane = t & 63, w = t >> 6;
  int wr = w >> 1, wc = w & 1;
  int g = lane >> 4, c = lane & 15;
  int m0 = blockIdx.y*128, n0 = blockIdx.x*128;
  f32x4 acc[4][4] = {};
  for (int k0 = 0; k0 < K; k0 += 64){
    stage_swz<4>(A  + (size_t)m0*K + k0, K, As, t);
    stage_swz<4>(Bt + (size_t)n0*K + k0, K, Bs, t);
    __syncthreads();
    #pragma unroll
    for (int kb2=0;kb2<2;kb2++){
      s8v af[4], bfr[4];
      #pragma unroll
      for (int m=0;m<4;m++) af[m]  = frag_ld(As, wr*64 + m*16 + c, kb2*4 + g);
      #pragma unroll
      for (int n=0;n<4;n++) bfr[n] = frag_ld(Bs, wc*64 + n*16 + c, kb2*4 + g);
      #pragma unroll
      for (int m=0;m<4;m++)
        #pragma unroll
        for (int n=0;n<4;n++)
          acc[m][n] = __builtin_amdgcn_mfma_f32_16x16x32_bf16(af[m], bfr[n], acc[m][n], 0, 0, 0);
    }
    __syncthreads();
  }
  #pragma unroll
  for (int m=0;m<4;m++){
    int growb = m0 + wr*64 + m*16 + g*4;
    #pragma unroll
    for (int n=0;n<4;n++){
      int gcol = n0 + wc*64 + n*16 + c;
      float bv = bias[gcol];
      if (EPI == 1){
        #pragma unroll
        for (int r=0;r<4;r++)
          Cout[(size_t)(growb + r)*Ntot + gcol] = acc[m][n][r] + bv;
      } else {
        int which = gcol / EMB;           // 0=Q 1=K 2=V (uniform per n-tile)
        int e = gcol - which*EMB;
        int hh = e >> 6, d = e & 63;
        int bi = growb >> 11, sb = growb & 2047;
        size_t bh = (size_t)bi*NH + hh;
        if (which == 2){
          ushort4 pv;
          pv.x = f2bf(acc[m][n][0] + bv);
          pv.y = f2bf(acc[m][n][1] + bv);
          pv.z = f2bf(acc[m][n][2] + bv);
          pv.w = f2bf(acc[m][n][3] + bv);
          *(ushort4*)(vT + (bh*HD + d)*SEQ + sb) = pv;
        } else {
          u16* dst = (which == 0) ? qb : kbf;
          float scl = (which == 0) ? QSCALE : 1.0f;
          #pragma unroll
          for (int r=0;r<4;r++)
            dst[(bh*SEQ + sb + r)*HD + d] = f2bf((acc[m][n][r] + bv)*scl);
        }
      }
    }
  }
}

// ------- causal flash attention: LDS dbuf + counted vmcnt + defer-max -----
__global__ __launch_bounds__(256) void attn_kernel(
    const u16* __restrict__ qb, const u16* __restrict__ kbf, const u16* __restrict__ vT,
    u16* __restrict__ attn)
{
  __shared__ u16 Kls[2][64*64];   // K tile [s][d], swizzled
  __shared__ u16 Vls[2][64*64];   // V^T tile [d][s], swizzled
  __shared__ u16 Ps[4][16*72];    // per-wave P[q=c][k], row stride 144B
  int bh = blockIdx.x;
  int b = bh / NH, h = bh - b*NH;
  int qt = 31 - blockIdx.y;
  int t = threadIdx.x, lane = t & 63, w = t >> 6;
  int g = lane >> 4, c = lane & 15;
  u16* pw = &Ps[w][0];
  const u16* Kb = kbf + (size_t)bh*SEQ*HD;
  const u16* Vb = vT  + (size_t)bh*HD*SEQ;

  int qwb = qt*64 + w*16;
  const u16* qrow = qb + ((size_t)bh*SEQ + qwb + c)*HD;
  s8v aq0 = *(const s8v*)(qrow + g*8);
  s8v aq1 = *(const s8v*)(qrow + 32 + g*8);
  f32x4 po[4] = {};
  float mrow = -1e30f, lrow = 0.f;      // per-lane: row q = c

  // prologue: stage tile 0 into buffer 0 (2 K + 2 V loads per thread)
  stage_swz<2>(Kb, HD, Kls[0], t);
  stage_swz<2>(Vb, SEQ, Vls[0], t);

  for (int kt = 0; kt <= qt; ++kt){
    int cur = kt & 1;
    const u16* Ks = Kls[cur];
    const u16* Vs = Vls[cur];
    if (kt < qt){
      int k1 = (kt + 1)*64;
      stage_swz<2>(Kb + (size_t)k1*HD, HD,  Kls[cur^1], t);
      stage_swz<2>(Vb + k1,            SEQ, Vls[cur^1], t);
      asm volatile("s_waitcnt vmcnt(4)" ::: "memory");   // tile t landed; t+1 in flight
    } else {
      asm volatile("s_waitcnt vmcnt(0)" ::: "memory");
    }
    __builtin_amdgcn_s_barrier();
    __builtin_amdgcn_sched_barrier(0);

    int k0 = kt*64;
    // V^T fragments early (consumed at PV; latency hides under QK^T+softmax)
    s8v vv[8];
    #pragma unroll
    for (int kb2=0;kb2<2;kb2++)
      #pragma unroll
      for (int dt=0;dt<4;dt++)
        vv[kb2*4+dt] = frag_ld(Vs, dt*16 + c, kb2*4 + g);
    // QK^T swapped: D = K·Q^T -> lane (c,g) holds S[q=c][k=k0+nt*16+g*4+r]
    f32x4 sc[4];
    __builtin_amdgcn_s_setprio(1);
    #pragma unroll
    for (int nt=0;nt<4;nt++){
      s8v k0f = frag_ld(Ks, nt*16 + c, g);
      s8v k1f = frag_ld(Ks, nt*16 + c, 4 + g);
      f32x4 z = {0.f,0.f,0.f,0.f};
      sc[nt] = __builtin_amdgcn_mfma_f32_16x16x32_bf16(k0f, aq0, z,      0,0,0);
      sc[nt] = __builtin_amdgcn_mfma_f32_16x16x32_bf16(k1f, aq1, sc[nt], 0,0,0);
    }
    __builtin_amdgcn_s_setprio(0);
    // causal mask (diagonal tile only): k = k0+nt*16+g*4+r, q = qwb+c
    if (kt == qt){
      #pragma unroll
      for (int nt=0;nt<4;nt++){
        int kg = k0 + nt*16 + g*4;
        #pragma unroll
        for (int r=0;r<4;r++)
          if (kg + r > qwb + c) sc[nt][r] = -1e30f;
      }
    }
    // row max: in-lane fmax tree + 2 shfl hops
    float mt = fmaxf(fmaxf(sc[0][0],sc[0][1]), fmaxf(sc[0][2],sc[0][3]));
    #pragma unroll
    for (int nt=1;nt<4;nt++)
      mt = fmaxf(mt, fmaxf(fmaxf(sc[nt][0],sc[nt][1]), fmaxf(sc[nt][2],sc[nt][3])));
    mt = fmaxf(mt, __shfl_xor(mt, 16));
    mt = fmaxf(mt, __shfl_xor(mt, 32));
    // defer-max (T13): only rescale when the running max grew by >8
    if (!__all(mt - mrow <= 8.0f)){
      float mn = fmaxf(mrow, mt);
      float alpha = exp2f(mrow - mn);
      mrow = mn;
      lrow *= alpha;
      float alB[4];
      #pragma unroll
      for (int r=0;r<4;r++)
        alB[r] = __shfl(alpha, (lane & 48) | (g*4 + r));
      #pragma unroll
      for (int dt=0;dt<4;dt++)
        #pragma unroll
        for (int r=0;r<4;r++)
          po[dt][r] *= alB[r];
    }
    float rs = 0.f;
    #pragma unroll
    for (int nt=0;nt<4;nt++)
      #pragma unroll
      for (int r=0;r<4;r++){
        float pe = exp2f(sc[nt][r] - mrow);
        sc[nt][r] = pe;
        rs += pe;
      }
    rs += __shfl_xor(rs, 16);
    rs += __shfl_xor(rs, 32);
    lrow += rs;
    // P -> wave-private LDS (redistribute k within 4-lane group), then PV
    #pragma unroll
    for (int nt=0;nt<4;nt++){
      ushort4 pk;
      pk.x = f2bf(sc[nt][0]); pk.y = f2bf(sc[nt][1]);
      pk.z = f2bf(sc[nt][2]); pk.w = f2bf(sc[nt][3]);
      *(ushort4*)(pw + c*72 + nt*16 + g*4) = pk;
    }
    __builtin_amdgcn_s_setprio(1);
    #pragma unroll
    for (int kb2=0;kb2<2;kb2++){
      s8v pa = *(const s8v*)(pw + c*72 + kb2*32 + g*8);
      #pragma unroll
      for (int dt=0;dt<4;dt++)
        po[dt] = __builtin_amdgcn_mfma_f32_16x16x32_bf16(pa, vv[kb2*4+dt], po[dt], 0,0,0);
    }
    __builtin_amdgcn_s_setprio(0);
    // all LDS reads retired before next iter's DMA may overwrite this buffer
    asm volatile("s_waitcnt lgkmcnt(0)" ::: "memory");
    __builtin_amdgcn_s_barrier();
  }
  // epilogue: broadcast 1/l from row-owner lanes, write O
  float inv = 1.0f / lrow;
  float invB[4];
  #pragma unroll
  for (int r=0;r<4;r++)
    invB[r] = __shfl(inv, (lane & 48) | (g*4 + r));
  #pragma unroll
  for (int dt=0;dt<4;dt++){
    #pragma unroll
    for (int r=0;r<4;r++){
      int qa = qwb + g*4 + r;
      attn[((size_t)(b*SEQ + qa))*EMB + h*HD + dt*16 + c] = f2bf(po[dt][r] * invB[r]);
    }
  }
}

extern "C" void kernel_launch(void* const* d_in, const int* in_sizes, int n_in,
                              void* d_out, int out_size, void* d_ws, size_t ws_size,
                              hipStream_t stream) {
  const float* hs    = (const float*)d_in[0];
  const float* qkv_w = (const float*)d_in[1];
  const float* qkv_b = (const float*)d_in[2];
  const float* out_w = (const float*)d_in[3];
  const float* out_b = (const float*)d_in[4];
  float* out = (float*)d_out;

  char* p = (char*)d_ws;
  u16* xb    = (u16*)p; p += (size_t)MT*EMB*2;
  u16* wqkvT = (u16*)p; p += (size_t)N3E*EMB*2;
  u16* woT   = (u16*)p; p += (size_t)EMB*EMB*2;
  u16* qbuf  = (u16*)p; p += (size_t)NB*NH*SEQ*HD*2;
  u16* kbuf  = (u16*)p; p += (size_t)NB*NH*SEQ*HD*2;
  u16* vTb   = (u16*)p; p += (size_t)NB*NH*SEQ*HD*2;
  u16* attnb = (u16*)p; p += (size_t)MT*EMB*2;

  prep_kernel<<<11520, 256, 0, stream>>>(hs, qkv_w, out_w, xb, wqkvT, woT);
  gemm_bt_kernel<0><<<dim3(N3E/128, MT/128), 256, 0, stream>>>(
      xb, wqkvT, qkv_b, nullptr, N3E, EMB, qbuf, kbuf, vTb);
  attn_kernel<<<dim3(40, 32), 256, 0, stream>>>(qbuf, kbuf, vTb, attnb);
  gemm_bt_kernel<1><<<dim3(EMB/128, MT/128), 256, 0, stream>>>(
      attnb, woT, out_b, out, EMB, EMB, nullptr, nullptr, nullptr);
}

// Round 6
// 252.163 us; speedup vs baseline: 1.4661x; 1.0084x over previous
//
#include <hip/hip_runtime.h>
#include <hip/hip_bf16.h>
#include <stdint.h>

typedef unsigned short u16;
typedef short s8v __attribute__((ext_vector_type(8)));
typedef float f32x4 __attribute__((ext_vector_type(4)));

#define NB 2
#define NH 20
#define SEQ 2048
#define EMB 1280
#define HD 64
#define MT (NB*SEQ)      // 4096
#define N3E (3*EMB)      // 3840
// Q pre-scale: 64^-0.5 * log2(e) -> softmax runs in exp2 domain
#define QSCALE 0.18033688011112042f

__device__ __forceinline__ u16 f2bf(float f){
  unsigned u = __float_as_uint(f);
  u += 0x7fffu + ((u >> 16) & 1u);   // round-to-nearest-even
  return (u16)(u >> 16);
}

// pack 2 floats -> 2 bf16 in one u32 (compiler emits v_cvt_pk_bf16_f32)
__device__ __forceinline__ unsigned pk2(float a, float b){
  __hip_bfloat162 h = __float22bfloat162_rn(float2{a, b});
  return *reinterpret_cast<unsigned*>(&h);
}

// ---- merged prep: fp32->bf16 convert of X + two transpose-converts -------
// blocks [0,5120): cvt X; [5120,9920): qkv_w^T; [9920,11520): out_w^T
__global__ __launch_bounds__(256) void prep_kernel(
    const float* __restrict__ hs, const float* __restrict__ qkv_w,
    const float* __restrict__ out_w,
    u16* __restrict__ xb, u16* __restrict__ wqkvT, u16* __restrict__ woT)
{
  __shared__ float tl[32][33];
  int blk = blockIdx.x;
  if (blk < 5120){
    int i = blk*256 + threadIdx.x;     // n4 = MT*EMB/4 = 1310720 = 5120*256
    float4 f = ((const float4* __restrict__)hs)[i];
    ushort4 o;
    o.x = f2bf(f.x); o.y = f2bf(f.y); o.z = f2bf(f.z); o.w = f2bf(f.w);
    ((ushort4*)xb)[i] = o;
    return;
  }
  const float* in; u16* out; int R, C, bx, by;
  if (blk < 9920){
    int b2 = blk - 5120; bx = b2 % 120; by = b2 / 120;
    in = qkv_w; out = wqkvT; R = EMB; C = N3E;
  } else {
    int b2 = blk - 9920; bx = b2 % 40; by = b2 / 40;
    in = out_w; out = woT; R = EMB; C = EMB;
  }
  int c0 = bx*32, r0 = by*32;
  int tx = threadIdx.x & 31, ty = threadIdx.x >> 5;   // 32x8
  #pragma unroll
  for (int i=0;i<4;i++)
    tl[ty + i*8][tx] = in[(size_t)(r0 + ty + i*8)*C + c0 + tx];
  __syncthreads();
  #pragma unroll
  for (int i=0;i<4;i++)
    out[(size_t)(c0 + ty + i*8)*R + r0 + tx] = f2bf(tl[tx][ty + i*8]);
}

// ---- swizzled global->LDS staging: rows of 128B (8 x 16B slots), XOR(row&7)
template<int NIT>
__device__ __forceinline__ void stage_swz(const u16* gsrc, int ld, u16* lds, int t){
  #pragma unroll
  for (int i=0;i<NIT;i++){
    int f = i*256 + t;
    int row = f >> 3, sl = f & 7;
    int ssl = sl ^ (row & 7);
    __builtin_amdgcn_global_load_lds(
      (const __attribute__((address_space(1))) void*)(gsrc + (size_t)row*ld + ssl*8),
      (__attribute__((address_space(3))) void*)(lds + f*8), 16, 0, 0);
  }
}

__device__ __forceinline__ s8v frag_ld(const u16* lds, int row, int ks){
  int sl = ks ^ (row & 7);
  return *(const s8v*)(lds + row*64 + sl*8);
}

// ---------------- GEMM: C[M][N] = A[M][K] @ Bt[N][K]^T + bias -------------
template<int EPI>
__global__ __launch_bounds__(256) void gemm_bt_kernel(
    const u16* __restrict__ A, const u16* __restrict__ Bt, const float* __restrict__ bias,
    float* __restrict__ Cout, int Ntot, int K,
    u16* __restrict__ qb, u16* __restrict__ kbf, u16* __restrict__ vT)
{
  __shared__ u16 As[128*64];
  __shared__ u16 Bs[128*64];
  int t = threadIdx.x;
  int lane = t & 63, w = t >> 6;
  int wr = w >> 1, wc = w & 1;
  int g = lane >> 4, c = lane & 15;
  int m0 = blockIdx.y*128, n0 = blockIdx.x*128;
  f32x4 acc[4][4] = {};
  for (int k0 = 0; k0 < K; k0 += 64){
    stage_swz<4>(A  + (size_t)m0*K + k0, K, As, t);
    stage_swz<4>(Bt + (size_t)n0*K + k0, K, Bs, t);
    __syncthreads();
    #pragma unroll
    for (int kb2=0;kb2<2;kb2++){
      s8v af[4], bfr[4];
      #pragma unroll
      for (int m=0;m<4;m++) af[m]  = frag_ld(As, wr*64 + m*16 + c, kb2*4 + g);
      #pragma unroll
      for (int n=0;n<4;n++) bfr[n] = frag_ld(Bs, wc*64 + n*16 + c, kb2*4 + g);
      #pragma unroll
      for (int m=0;m<4;m++)
        #pragma unroll
        for (int n=0;n<4;n++)
          acc[m][n] = __builtin_amdgcn_mfma_f32_16x16x32_bf16(af[m], bfr[n], acc[m][n], 0, 0, 0);
    }
    __syncthreads();
  }
  #pragma unroll
  for (int m=0;m<4;m++){
    int growb = m0 + wr*64 + m*16 + g*4;
    #pragma unroll
    for (int n=0;n<4;n++){
      int gcol = n0 + wc*64 + n*16 + c;
      float bv = bias[gcol];
      if (EPI == 1){
        #pragma unroll
        for (int r=0;r<4;r++)
          Cout[(size_t)(growb + r)*Ntot + gcol] = acc[m][n][r] + bv;
      } else {
        int which = gcol / EMB;           // 0=Q 1=K 2=V (uniform per n-tile)
        int e = gcol - which*EMB;
        int hh = e >> 6, d = e & 63;
        int bi = growb >> 11, sb = growb & 2047;
        size_t bh = (size_t)bi*NH + hh;
        if (which == 2){
          uint2 pv2;
          pv2.x = pk2(acc[m][n][0] + bv, acc[m][n][1] + bv);
          pv2.y = pk2(acc[m][n][2] + bv, acc[m][n][3] + bv);
          *(uint2*)(vT + (bh*HD + d)*SEQ + sb) = pv2;
        } else {
          u16* dst = (which == 0) ? qb : kbf;
          float scl = (which == 0) ? QSCALE : 1.0f;
          #pragma unroll
          for (int r=0;r<4;r++)
            dst[(bh*SEQ + sb + r)*HD + d] = f2bf((acc[m][n][r] + bv)*scl);
        }
      }
    }
  }
}

// ------- causal flash attention: dbuf + counted vmcnt + O^T PV ------------
// grid (bh=40, 32); qt = 31-by. 4 waves own 16 q-rows each. Swapped QK^T:
// lane owns q-row (lane&15) for softmax. PV computed as O^T = mfma(V^T, P^T)
// so po's q-index is ALSO lane&15 -> alpha/1/l apply per-lane, no broadcasts.
// LDS exactly 40960 B -> 4 blocks/CU.
__global__ __launch_bounds__(256) void attn_kernel(
    const u16* __restrict__ qb, const u16* __restrict__ kbf, const u16* __restrict__ vT,
    u16* __restrict__ attn)
{
  __shared__ u16 Kls[2][64*64];   // K tile [s][d], swizzled     (16 KB)
  __shared__ u16 Vls[2][64*64];   // V^T tile [d][s], swizzled   (16 KB)
  __shared__ u16 Ps[4][1024];     // per-wave P[q=c][k], XOR-swizzled (8 KB)
  int bh = blockIdx.x;
  int b = bh / NH, h = bh - b*NH;
  int qt = 31 - blockIdx.y;
  int t = threadIdx.x, lane = t & 63, w = t >> 6;
  int g = lane >> 4, c = lane & 15;
  u16* pw = &Ps[w][0];
  const u16* Kb = kbf + (size_t)bh*SEQ*HD;
  const u16* Vb = vT  + (size_t)bh*HD*SEQ;

  int qwb = qt*64 + w*16;
  const u16* qrow = qb + ((size_t)bh*SEQ + qwb + c)*HD;
  s8v aq0 = *(const s8v*)(qrow + g*8);
  s8v aq1 = *(const s8v*)(qrow + 32 + g*8);
  f32x4 po[4] = {};                     // O^T: po[dt][r] = O[d=dt*16+g*4+r][q=c]
  float mrow = -1e30f, lrow = 0.f;      // per-lane: row q = c
  int cswz = 2*(c & 7);                 // P-slot XOR key

  // prologue: stage tile 0 into buffer 0 (2 K + 2 V loads per thread)
  stage_swz<2>(Kb, HD, Kls[0], t);
  stage_swz<2>(Vb, SEQ, Vls[0], t);

  for (int kt = 0; kt <= qt; ++kt){
    int cur = kt & 1;
    const u16* Ks = Kls[cur];
    const u16* Vs = Vls[cur];
    if (kt < qt){
      int k1 = (kt + 1)*64;
      stage_swz<2>(Kb + (size_t)k1*HD, HD,  Kls[cur^1], t);
      stage_swz<2>(Vb + k1,            SEQ, Vls[cur^1], t);
      asm volatile("s_waitcnt vmcnt(4)" ::: "memory");   // tile t landed; t+1 in flight
    } else {
      asm volatile("s_waitcnt vmcnt(0)" ::: "memory");
    }
    __builtin_amdgcn_s_barrier();
    __builtin_amdgcn_sched_barrier(0);

    int k0 = kt*64;
    // V^T fragments early (consumed at PV; latency hides under QK^T+softmax)
    s8v vv[8];
    #pragma unroll
    for (int kb2=0;kb2<2;kb2++)
      #pragma unroll
      for (int dt=0;dt<4;dt++)
        vv[kb2*4+dt] = frag_ld(Vs, dt*16 + c, kb2*4 + g);
    // QK^T swapped: D = K·Q^T -> lane (c,g) holds S[q=c][k=k0+nt*16+g*4+r]
    f32x4 sc[4];
    __builtin_amdgcn_s_setprio(1);
    #pragma unroll
    for (int nt=0;nt<4;nt++){
      s8v k0f = frag_ld(Ks, nt*16 + c, g);
      s8v k1f = frag_ld(Ks, nt*16 + c, 4 + g);
      f32x4 z = {0.f,0.f,0.f,0.f};
      sc[nt] = __builtin_amdgcn_mfma_f32_16x16x32_bf16(k0f, aq0, z,      0,0,0);
      sc[nt] = __builtin_amdgcn_mfma_f32_16x16x32_bf16(k1f, aq1, sc[nt], 0,0,0);
    }
    __builtin_amdgcn_s_setprio(0);
    // causal mask (diagonal tile only): k = k0+nt*16+g*4+r, q = qwb+c
    if (kt == qt){
      #pragma unroll
      for (int nt=0;nt<4;nt++){
        int kg = k0 + nt*16 + g*4;
        #pragma unroll
        for (int r=0;r<4;r++)
          if (kg + r > qwb + c) sc[nt][r] = -1e30f;
      }
    }
    // row max: in-lane fmax tree + 2 shfl hops (syncs all 4 g-copies of row c)
    float mt = fmaxf(fmaxf(sc[0][0],sc[0][1]), fmaxf(sc[0][2],sc[0][3]));
    #pragma unroll
    for (int nt=1;nt<4;nt++)
      mt = fmaxf(mt, fmaxf(fmaxf(sc[nt][0],sc[nt][1]), fmaxf(sc[nt][2],sc[nt][3])));
    mt = fmaxf(mt, __shfl_xor(mt, 16));
    mt = fmaxf(mt, __shfl_xor(mt, 32));
    // defer-max (T13): only rescale when the running max grew by >8
    if (!__all(mt - mrow <= 8.0f)){
      float mn = fmaxf(mrow, mt);
      float alpha = exp2f(mrow - mn);
      mrow = mn;
      lrow *= alpha;
      #pragma unroll
      for (int dt=0;dt<4;dt++)
        #pragma unroll
        for (int r=0;r<4;r++)
          po[dt][r] *= alpha;           // po q-index == c -> per-lane alpha
    }
    float rs = 0.f;
    #pragma unroll
    for (int nt=0;nt<4;nt++)
      #pragma unroll
      for (int r=0;r<4;r++){
        float pe = exp2f(sc[nt][r] - mrow);
        sc[nt][r] = pe;
        rs += pe;
      }
    rs += __shfl_xor(rs, 16);
    rs += __shfl_xor(rs, 32);
    lrow += rs;
    // P -> wave-private LDS, XOR-swizzled 8B slots (cvt_pk packing)
    #pragma unroll
    for (int nt=0;nt<4;nt++){
      uint2 pk;
      pk.x = pk2(sc[nt][0], sc[nt][1]);
      pk.y = pk2(sc[nt][2], sc[nt][3]);
      *(uint2*)(pw + c*64 + ((nt*4 + g) ^ cswz)*4) = pk;
    }
    // PV as O^T: po[dt] = mfma(A=V^T frag, B=P^T frag)
    __builtin_amdgcn_s_setprio(1);
    #pragma unroll
    for (int kb2=0;kb2<2;kb2++){
      s8v pa = *(const s8v*)(pw + c*64 + ((kb2*8 + 2*g) ^ cswz)*4);
      #pragma unroll
      for (int dt=0;dt<4;dt++)
        po[dt] = __builtin_amdgcn_mfma_f32_16x16x32_bf16(vv[kb2*4+dt], pa, po[dt], 0,0,0);
    }
    __builtin_amdgcn_s_setprio(0);
    // all LDS reads retired before next iter's DMA may overwrite this buffer
    asm volatile("s_waitcnt lgkmcnt(0)" ::: "memory");
    __builtin_amdgcn_s_barrier();
  }
  // epilogue: per-lane 1/l (q=c), vectorized 8B stores of O row q
  float inv = 1.0f / lrow;
  const size_t orow = ((size_t)(b*SEQ + qwb + c))*EMB + h*HD;
  #pragma unroll
  for (int dt=0;dt<4;dt++){
    uint2 o;
    o.x = pk2(po[dt][0]*inv, po[dt][1]*inv);
    o.y = pk2(po[dt][2]*inv, po[dt][3]*inv);
    *(uint2*)(attn + orow + dt*16 + g*4) = o;
  }
}

extern "C" void kernel_launch(void* const* d_in, const int* in_sizes, int n_in,
                              void* d_out, int out_size, void* d_ws, size_t ws_size,
                              hipStream_t stream) {
  const float* hs    = (const float*)d_in[0];
  const float* qkv_w = (const float*)d_in[1];
  const float* qkv_b = (const float*)d_in[2];
  const float* out_w = (const float*)d_in[3];
  const float* out_b = (const float*)d_in[4];
  float* out = (float*)d_out;

  char* p = (char*)d_ws;
  u16* xb    = (u16*)p; p += (size_t)MT*EMB*2;
  u16* wqkvT = (u16*)p; p += (size_t)N3E*EMB*2;
  u16* woT   = (u16*)p; p += (size_t)EMB*EMB*2;
  u16* qbuf  = (u16*)p; p += (size_t)NB*NH*SEQ*HD*2;
  u16* kbuf  = (u16*)p; p += (size_t)NB*NH*SEQ*HD*2;
  u16* vTb   = (u16*)p; p += (size_t)NB*NH*SEQ*HD*2;
  u16* attnb = (u16*)p; p += (size_t)MT*EMB*2;

  prep_kernel<<<11520, 256, 0, stream>>>(hs, qkv_w, out_w, xb, wqkvT, woT);
  gemm_bt_kernel<0><<<dim3(N3E/128, MT/128), 256, 0, stream>>>(
      xb, wqkvT, qkv_b, nullptr, N3E, EMB, qbuf, kbuf, vTb);
  attn_kernel<<<dim3(40, 32), 256, 0, stream>>>(qbuf, kbuf, vTb, attnb);
  gemm_bt_kernel<1><<<dim3(EMB/128, MT/128), 256, 0, stream>>>(
      attnb, woT, out_b, out, EMB, EMB, nullptr, nullptr, nullptr);
}

// Round 7
// 242.262 us; speedup vs baseline: 1.5260x; 1.0409x over previous
//
#include <hip/hip_runtime.h>
#include <hip/hip_bf16.h>
#include <stdint.h>

typedef unsigned short u16;
typedef short s8v __attribute__((ext_vector_type(8)));
typedef float f32x4 __attribute__((ext_vector_type(4)));

#define NB 2
#define NH 20
#define SEQ 2048
#define EMB 1280
#define HD 64
#define MT (NB*SEQ)      // 4096
#define N3E (3*EMB)      // 3840
// Q pre-scale: 64^-0.5 * log2(e) -> softmax runs in exp2 domain
#define QSCALE 0.18033688011112042f

__device__ __forceinline__ u16 f2bf(float f){
  unsigned u = __float_as_uint(f);
  u += 0x7fffu + ((u >> 16) & 1u);   // round-to-nearest-even
  return (u16)(u >> 16);
}

// pack 2 floats -> 2 bf16 in one u32 (compiler emits v_cvt_pk_bf16_f32)
__device__ __forceinline__ unsigned pk2(float a, float b){
  __hip_bfloat162 h = __float22bfloat162_rn(float2{a, b});
  return *reinterpret_cast<unsigned*>(&h);
}

// ---- merged prep: fp32->bf16 convert of X + two transpose-converts -------
// blocks [0,5120): cvt X; [5120,9920): qkv_w^T; [9920,11520): out_w^T
__global__ __launch_bounds__(256) void prep_kernel(
    const float* __restrict__ hs, const float* __restrict__ qkv_w,
    const float* __restrict__ out_w,
    u16* __restrict__ xb, u16* __restrict__ wqkvT, u16* __restrict__ woT)
{
  __shared__ float tl[32][33];
  int blk = blockIdx.x;
  if (blk < 5120){
    int i = blk*256 + threadIdx.x;     // n4 = MT*EMB/4 = 1310720 = 5120*256
    float4 f = ((const float4* __restrict__)hs)[i];
    ushort4 o;
    o.x = f2bf(f.x); o.y = f2bf(f.y); o.z = f2bf(f.z); o.w = f2bf(f.w);
    ((ushort4*)xb)[i] = o;
    return;
  }
  const float* in; u16* out; int R, C, bx, by;
  if (blk < 9920){
    int b2 = blk - 5120; bx = b2 % 120; by = b2 / 120;
    in = qkv_w; out = wqkvT; R = EMB; C = N3E;
  } else {
    int b2 = blk - 9920; bx = b2 % 40; by = b2 / 40;
    in = out_w; out = woT; R = EMB; C = EMB;
  }
  int c0 = bx*32, r0 = by*32;
  int tx = threadIdx.x & 31, ty = threadIdx.x >> 5;   // 32x8
  #pragma unroll
  for (int i=0;i<4;i++)
    tl[ty + i*8][tx] = in[(size_t)(r0 + ty + i*8)*C + c0 + tx];
  __syncthreads();
  #pragma unroll
  for (int i=0;i<4;i++)
    out[(size_t)(c0 + ty + i*8)*R + r0 + tx] = f2bf(tl[tx][ty + i*8]);
}

// ---- swizzled global->LDS staging: rows of 128B (8 x 16B slots), XOR(row&7)
template<int NIT>
__device__ __forceinline__ void stage_swz(const u16* gsrc, int ld, u16* lds, int t){
  #pragma unroll
  for (int i=0;i<NIT;i++){
    int f = i*256 + t;
    int row = f >> 3, sl = f & 7;
    int ssl = sl ^ (row & 7);
    __builtin_amdgcn_global_load_lds(
      (const __attribute__((address_space(1))) void*)(gsrc + (size_t)row*ld + ssl*8),
      (__attribute__((address_space(3))) void*)(lds + f*8), 16, 0, 0);
  }
}

__device__ __forceinline__ s8v frag_ld(const u16* lds, int row, int ks){
  int sl = ks ^ (row & 7);
  return *(const s8v*)(lds + row*64 + sl*8);
}

// ------- GEMM: C[M][N] = A[M][K] @ Bt[N][K]^T + bias ----------------------
// Double-buffered LDS + counted vmcnt (attn-proven pattern): tile t+1's 8
// DMA loads stay in flight across tile t's compute; never drain mid-loop.
template<int EPI>
__global__ __launch_bounds__(256) void gemm_bt_kernel(
    const u16* __restrict__ A, const u16* __restrict__ Bt, const float* __restrict__ bias,
    float* __restrict__ Cout, int Ntot, int K,
    u16* __restrict__ qb, u16* __restrict__ kbf, u16* __restrict__ vT)
{
  __shared__ u16 As[2][128*64];
  __shared__ u16 Bs[2][128*64];
  int t = threadIdx.x;
  int lane = t & 63, w = t >> 6;
  int wr = w >> 1, wc = w & 1;
  int g = lane >> 4, c = lane & 15;
  int m0 = blockIdx.y*128, n0 = blockIdx.x*128;
  const u16* Ab = A  + (size_t)m0*K;
  const u16* Bb = Bt + (size_t)n0*K;
  f32x4 acc[4][4] = {};
  int NT = K/64;
  // prologue: stage tile 0 into buffer 0
  stage_swz<4>(Ab, K, As[0], t);
  stage_swz<4>(Bb, K, Bs[0], t);
  for (int kt = 0; kt < NT; ++kt){
    int d = kt & 1;
    if (kt < NT-1){
      int k1 = (kt+1)*64;
      stage_swz<4>(Ab + k1, K, As[d^1], t);
      stage_swz<4>(Bb + k1, K, Bs[d^1], t);
      asm volatile("s_waitcnt vmcnt(8)" ::: "memory");   // tile t landed; t+1 in flight
    } else {
      asm volatile("s_waitcnt vmcnt(0)" ::: "memory");
    }
    __builtin_amdgcn_s_barrier();
    __builtin_amdgcn_sched_barrier(0);
    #pragma unroll
    for (int kb2=0;kb2<2;kb2++){
      s8v af[4], bfr[4];
      #pragma unroll
      for (int m=0;m<4;m++) af[m]  = frag_ld(As[d], wr*64 + m*16 + c, kb2*4 + g);
      #pragma unroll
      for (int n=0;n<4;n++) bfr[n] = frag_ld(Bs[d], wc*64 + n*16 + c, kb2*4 + g);
      #pragma unroll
      for (int m=0;m<4;m++)
        #pragma unroll
        for (int n=0;n<4;n++)
          acc[m][n] = __builtin_amdgcn_mfma_f32_16x16x32_bf16(af[m], bfr[n], acc[m][n], 0, 0, 0);
    }
    // all LDS reads of buf d retired before iter t+2 DMAs into it
    asm volatile("s_waitcnt lgkmcnt(0)" ::: "memory");
    __builtin_amdgcn_s_barrier();
  }
  #pragma unroll
  for (int m=0;m<4;m++){
    int growb = m0 + wr*64 + m*16 + g*4;
    #pragma unroll
    for (int n=0;n<4;n++){
      int gcol = n0 + wc*64 + n*16 + c;
      float bv = bias[gcol];
      if (EPI == 1){
        #pragma unroll
        for (int r=0;r<4;r++)
          Cout[(size_t)(growb + r)*Ntot + gcol] = acc[m][n][r] + bv;
      } else {
        int which = gcol / EMB;           // 0=Q 1=K 2=V (uniform per n-tile)
        int e = gcol - which*EMB;
        int hh = e >> 6, d2 = e & 63;
        int bi = growb >> 11, sb = growb & 2047;
        size_t bh = (size_t)bi*NH + hh;
        if (which == 2){
          uint2 pv2;
          pv2.x = pk2(acc[m][n][0] + bv, acc[m][n][1] + bv);
          pv2.y = pk2(acc[m][n][2] + bv, acc[m][n][3] + bv);
          *(uint2*)(vT + (bh*HD + d2)*SEQ + sb) = pv2;
        } else {
          u16* dst = (which == 0) ? qb : kbf;
          float scl = (which == 0) ? QSCALE : 1.0f;
          #pragma unroll
          for (int r=0;r<4;r++)
            dst[(bh*SEQ + sb + r)*HD + d2] = f2bf((acc[m][n][r] + bv)*scl);
        }
      }
    }
  }
}

// ------- causal flash attention: dbuf + counted vmcnt + O^T PV ------------
// grid (bh=40, 32); qt = 31-by. 4 waves own 16 q-rows each. Swapped QK^T:
// lane owns q-row (lane&15) for softmax. PV computed as O^T = mfma(V^T, P^T)
// so po's q-index is ALSO lane&15 -> alpha/1/l apply per-lane, no broadcasts.
__global__ __launch_bounds__(256) void attn_kernel(
    const u16* __restrict__ qb, const u16* __restrict__ kbf, const u16* __restrict__ vT,
    u16* __restrict__ attn)
{
  __shared__ u16 Kls[2][64*64];   // K tile [s][d], swizzled     (16 KB)
  __shared__ u16 Vls[2][64*64];   // V^T tile [d][s], swizzled   (16 KB)
  __shared__ u16 Ps[4][1024];     // per-wave P[q=c][k], XOR-swizzled (8 KB)
  int bh = blockIdx.x;
  int b = bh / NH, h = bh - b*NH;
  int qt = 31 - blockIdx.y;
  int t = threadIdx.x, lane = t & 63, w = t >> 6;
  int g = lane >> 4, c = lane & 15;
  u16* pw = &Ps[w][0];
  const u16* Kb = kbf + (size_t)bh*SEQ*HD;
  const u16* Vb = vT  + (size_t)bh*HD*SEQ;

  int qwb = qt*64 + w*16;
  const u16* qrow = qb + ((size_t)bh*SEQ + qwb + c)*HD;
  s8v aq0 = *(const s8v*)(qrow + g*8);
  s8v aq1 = *(const s8v*)(qrow + 32 + g*8);
  f32x4 po[4] = {};                     // O^T: po[dt][r] = O[d=dt*16+g*4+r][q=c]
  float mrow = -1e30f, lrow = 0.f;      // per-lane: row q = c
  int cswz = 2*(c & 7);                 // P-slot XOR key

  // prologue: stage tile 0 into buffer 0 (2 K + 2 V loads per thread)
  stage_swz<2>(Kb, HD, Kls[0], t);
  stage_swz<2>(Vb, SEQ, Vls[0], t);

  for (int kt = 0; kt <= qt; ++kt){
    int cur = kt & 1;
    const u16* Ks = Kls[cur];
    const u16* Vs = Vls[cur];
    if (kt < qt){
      int k1 = (kt + 1)*64;
      stage_swz<2>(Kb + (size_t)k1*HD, HD,  Kls[cur^1], t);
      stage_swz<2>(Vb + k1,            SEQ, Vls[cur^1], t);
      asm volatile("s_waitcnt vmcnt(4)" ::: "memory");   // tile t landed; t+1 in flight
    } else {
      asm volatile("s_waitcnt vmcnt(0)" ::: "memory");
    }
    __builtin_amdgcn_s_barrier();
    __builtin_amdgcn_sched_barrier(0);

    int k0 = kt*64;
    // V^T fragments early (consumed at PV; latency hides under QK^T+softmax)
    s8v vv[8];
    #pragma unroll
    for (int kb2=0;kb2<2;kb2++)
      #pragma unroll
      for (int dt=0;dt<4;dt++)
        vv[kb2*4+dt] = frag_ld(Vs, dt*16 + c, kb2*4 + g);
    // QK^T swapped: D = K·Q^T -> lane (c,g) holds S[q=c][k=k0+nt*16+g*4+r]
    f32x4 sc[4];
    __builtin_amdgcn_s_setprio(1);
    #pragma unroll
    for (int nt=0;nt<4;nt++){
      s8v k0f = frag_ld(Ks, nt*16 + c, g);
      s8v k1f = frag_ld(Ks, nt*16 + c, 4 + g);
      f32x4 z = {0.f,0.f,0.f,0.f};
      sc[nt] = __builtin_amdgcn_mfma_f32_16x16x32_bf16(k0f, aq0, z,      0,0,0);
      sc[nt] = __builtin_amdgcn_mfma_f32_16x16x32_bf16(k1f, aq1, sc[nt], 0,0,0);
    }
    __builtin_amdgcn_s_setprio(0);
    // causal mask (diagonal tile only): k = k0+nt*16+g*4+r, q = qwb+c
    if (kt == qt){
      #pragma unroll
      for (int nt=0;nt<4;nt++){
        int kg = k0 + nt*16 + g*4;
        #pragma unroll
        for (int r=0;r<4;r++)
          if (kg + r > qwb + c) sc[nt][r] = -1e30f;
      }
    }
    // row max: in-lane fmax tree + 2 shfl hops (syncs all 4 g-copies of row c)
    float mt = fmaxf(fmaxf(sc[0][0],sc[0][1]), fmaxf(sc[0][2],sc[0][3]));
    #pragma unroll
    for (int nt=1;nt<4;nt++)
      mt = fmaxf(mt, fmaxf(fmaxf(sc[nt][0],sc[nt][1]), fmaxf(sc[nt][2],sc[nt][3])));
    mt = fmaxf(mt, __shfl_xor(mt, 16));
    mt = fmaxf(mt, __shfl_xor(mt, 32));
    // defer-max (T13): only rescale when the running max grew by >8
    if (!__all(mt - mrow <= 8.0f)){
      float mn = fmaxf(mrow, mt);
      float alpha = exp2f(mrow - mn);
      mrow = mn;
      lrow *= alpha;
      #pragma unroll
      for (int dt=0;dt<4;dt++)
        #pragma unroll
        for (int r=0;r<4;r++)
          po[dt][r] *= alpha;           // po q-index == c -> per-lane alpha
    }
    float rs = 0.f;
    #pragma unroll
    for (int nt=0;nt<4;nt++)
      #pragma unroll
      for (int r=0;r<4;r++){
        float pe = exp2f(sc[nt][r] - mrow);
        sc[nt][r] = pe;
        rs += pe;
      }
    rs += __shfl_xor(rs, 16);
    rs += __shfl_xor(rs, 32);
    lrow += rs;
    // P -> wave-private LDS, XOR-swizzled 8B slots (cvt_pk packing)
    #pragma unroll
    for (int nt=0;nt<4;nt++){
      uint2 pk;
      pk.x = pk2(sc[nt][0], sc[nt][1]);
      pk.y = pk2(sc[nt][2], sc[nt][3]);
      *(uint2*)(pw + c*64 + ((nt*4 + g) ^ cswz)*4) = pk;
    }
    // PV as O^T: po[dt] = mfma(A=V^T frag, B=P^T frag)
    __builtin_amdgcn_s_setprio(1);
    #pragma unroll
    for (int kb2=0;kb2<2;kb2++){
      s8v pa = *(const s8v*)(pw + c*64 + ((kb2*8 + 2*g) ^ cswz)*4);
      #pragma unroll
      for (int dt=0;dt<4;dt++)
        po[dt] = __builtin_amdgcn_mfma_f32_16x16x32_bf16(vv[kb2*4+dt], pa, po[dt], 0,0,0);
    }
    __builtin_amdgcn_s_setprio(0);
    // all LDS reads retired before next iter's DMA may overwrite this buffer
    asm volatile("s_waitcnt lgkmcnt(0)" ::: "memory");
    __builtin_amdgcn_s_barrier();
  }
  // epilogue: per-lane 1/l (q=c), vectorized 8B stores of O row q
  float inv = 1.0f / lrow;
  const size_t orow = ((size_t)(b*SEQ + qwb + c))*EMB + h*HD;
  #pragma unroll
  for (int dt=0;dt<4;dt++){
    uint2 o;
    o.x = pk2(po[dt][0]*inv, po[dt][1]*inv);
    o.y = pk2(po[dt][2]*inv, po[dt][3]*inv);
    *(uint2*)(attn + orow + dt*16 + g*4) = o;
  }
}

extern "C" void kernel_launch(void* const* d_in, const int* in_sizes, int n_in,
                              void* d_out, int out_size, void* d_ws, size_t ws_size,
                              hipStream_t stream) {
  const float* hs    = (const float*)d_in[0];
  const float* qkv_w = (const float*)d_in[1];
  const float* qkv_b = (const float*)d_in[2];
  const float* out_w = (const float*)d_in[3];
  const float* out_b = (const float*)d_in[4];
  float* out = (float*)d_out;

  char* p = (char*)d_ws;
  u16* xb    = (u16*)p; p += (size_t)MT*EMB*2;
  u16* wqkvT = (u16*)p; p += (size_t)N3E*EMB*2;
  u16* woT   = (u16*)p; p += (size_t)EMB*EMB*2;
  u16* qbuf  = (u16*)p; p += (size_t)NB*NH*SEQ*HD*2;
  u16* kbuf  = (u16*)p; p += (size_t)NB*NH*SEQ*HD*2;
  u16* vTb   = (u16*)p; p += (size_t)NB*NH*SEQ*HD*2;
  u16* attnb = (u16*)p; p += (size_t)MT*EMB*2;

  prep_kernel<<<11520, 256, 0, stream>>>(hs, qkv_w, out_w, xb, wqkvT, woT);
  gemm_bt_kernel<0><<<dim3(N3E/128, MT/128), 256, 0, stream>>>(
      xb, wqkvT, qkv_b, nullptr, N3E, EMB, qbuf, kbuf, vTb);
  attn_kernel<<<dim3(40, 32), 256, 0, stream>>>(qbuf, kbuf, vTb, attnb);
  gemm_bt_kernel<1><<<dim3(EMB/128, MT/128), 256, 0, stream>>>(
      attnb, woT, out_b, out, EMB, EMB, nullptr, nullptr, nullptr);
}

// Round 8
// 229.932 us; speedup vs baseline: 1.6078x; 1.0536x over previous
//
#include <hip/hip_runtime.h>
#include <hip/hip_bf16.h>
#include <stdint.h>

typedef unsigned short u16;
typedef short s8v __attribute__((ext_vector_type(8)));
typedef float f32x4 __attribute__((ext_vector_type(4)));

#define NB 2
#define NH 20
#define SEQ 2048
#define EMB 1280
#define HD 64
#define MT (NB*SEQ)      // 4096
#define N3E (3*EMB)      // 3840
// Q pre-scale: 64^-0.5 * log2(e) -> softmax runs in exp2 domain
#define QSCALE 0.18033688011112042f

__device__ __forceinline__ u16 f2bf(float f){
  unsigned u = __float_as_uint(f);
  u += 0x7fffu + ((u >> 16) & 1u);   // round-to-nearest-even
  return (u16)(u >> 16);
}

// pack 2 floats -> 2 bf16 in one u32 (compiler emits v_cvt_pk_bf16_f32)
__device__ __forceinline__ unsigned pk2(float a, float b){
  __hip_bfloat162 h = __float22bfloat162_rn(float2{a, b});
  return *reinterpret_cast<unsigned*>(&h);
}

// ---- merged prep: fp32->bf16 convert of X + two transpose-converts -------
__global__ __launch_bounds__(256) void prep_kernel(
    const float* __restrict__ hs, const float* __restrict__ qkv_w,
    const float* __restrict__ out_w,
    u16* __restrict__ xb, u16* __restrict__ wqkvT, u16* __restrict__ woT)
{
  __shared__ float tl[32][33];
  int blk = blockIdx.x;
  if (blk < 5120){
    int i = blk*256 + threadIdx.x;     // n4 = MT*EMB/4 = 1310720 = 5120*256
    float4 f = ((const float4* __restrict__)hs)[i];
    ushort4 o;
    o.x = f2bf(f.x); o.y = f2bf(f.y); o.z = f2bf(f.z); o.w = f2bf(f.w);
    ((ushort4*)xb)[i] = o;
    return;
  }
  const float* in; u16* out; int R, C, bx, by;
  if (blk < 9920){
    int b2 = blk - 5120; bx = b2 % 120; by = b2 / 120;
    in = qkv_w; out = wqkvT; R = EMB; C = N3E;
  } else {
    int b2 = blk - 9920; bx = b2 % 40; by = b2 / 40;
    in = out_w; out = woT; R = EMB; C = EMB;
  }
  int c0 = bx*32, r0 = by*32;
  int tx = threadIdx.x & 31, ty = threadIdx.x >> 5;   // 32x8
  #pragma unroll
  for (int i=0;i<4;i++)
    tl[ty + i*8][tx] = in[(size_t)(r0 + ty + i*8)*C + c0 + tx];
  __syncthreads();
  #pragma unroll
  for (int i=0;i<4;i++)
    out[(size_t)(c0 + ty + i*8)*R + r0 + tx] = f2bf(tl[tx][ty + i*8]);
}

// ---- swizzled global->LDS staging: rows of 128B (8 x 16B slots), XOR(row&7)
template<int NIT>
__device__ __forceinline__ void stage_swz(const u16* gsrc, int ld, u16* lds, int t){
  #pragma unroll
  for (int i=0;i<NIT;i++){
    int f = i*256 + t;
    int row = f >> 3, sl = f & 7;
    int ssl = sl ^ (row & 7);
    __builtin_amdgcn_global_load_lds(
      (const __attribute__((address_space(1))) void*)(gsrc + (size_t)row*ld + ssl*8),
      (__attribute__((address_space(3))) void*)(lds + f*8), 16, 0, 0);
  }
}

// 512-thread variant: one 128x64 half-tile (16KB) = 2 loads/thread
__device__ __forceinline__ void stage_half(const u16* gsrc, int ld, u16* lds, int t){
  #pragma unroll
  for (int i=0;i<2;i++){
    int f = i*512 + t;
    int row = f >> 3, sl = f & 7;
    int ssl = sl ^ (row & 7);
    __builtin_amdgcn_global_load_lds(
      (const __attribute__((address_space(1))) void*)(gsrc + (size_t)row*ld + ssl*8),
      (__attribute__((address_space(3))) void*)(lds + f*8), 16, 0, 0);
  }
}

__device__ __forceinline__ s8v frag_ld(const u16* lds, int row, int ks){
  int sl = ks ^ (row & 7);
  return *(const s8v*)(lds + row*64 + sl*8);
}

#define MFMA16(a,b,c) __builtin_amdgcn_mfma_f32_16x16x32_bf16(a,b,c,0,0,0)

// ===== 256^2 8-phase GEMM (QKV projection, EPI0 scatter) ==================
// 512 thr (8 waves 2x4), BK=64, LDS 128KB (2 buf x [A 256x64 | B 256x64]).
// Wave rows: m<4 -> A-half0 (rows wr*64+m*16), m>=4 -> A-half1 (128+...).
// Wave cols: n<2 -> B-half0 (wc*32+n*16), n>=2 -> B-half1 (128+...).
// Phases per tile: P1(mh0,nh0) P2(mh0,nh1) P3(mh1,nh0) P4(mh1,nh1).
// LDS last-reads: A0,B0 @P1; B1 @P2; A1 @P3 -> stage t+2's A0 @P3, B0 @P4
// into CURRENT buffer; t+1's A1 @P1, B1 @P2 into other buffer.
// vmcnt(4) once per tile boundary (2 halves stay in flight); drain at end.
__global__ __launch_bounds__(512, 2) void gemm256_qkv_kernel(
    const u16* __restrict__ A, const u16* __restrict__ Bt, const float* __restrict__ bias,
    u16* __restrict__ qb, u16* __restrict__ kbf, u16* __restrict__ vT)
{
  const int K = EMB, NT = EMB/64;      // 20 K-tiles
  __shared__ u16 As[2][256*64];
  __shared__ u16 Bs[2][256*64];
  int t = threadIdx.x;
  int lane = t & 63, w = t >> 6;
  int wr = w >> 2, wc = w & 3;
  int g = lane >> 4, c = lane & 15;
  // bijective XCD swizzle (nwg=240, 240%8==0): 30 consecutive ids per XCD
  int o = blockIdx.x;
  int sw = (o & 7)*30 + (o >> 3);
  int bxs = sw >> 4;                   // 0..14 (N)
  int bys = sw & 15;                   // 0..15 (M)
  int m0 = bys*256, n0 = bxs*256;
  const u16* Ab = A  + (size_t)m0*K;
  const u16* Bb = Bt + (size_t)n0*K;
  f32x4 acc[8][4] = {};
  s8v af[8], bf0[4], bf1[4];

  // prologue: tile0 (4 halves) + tile1's A0,B0; vmcnt(4) -> tile0 landed
  stage_half(Ab,                        K, &As[0][0],        t);
  stage_half(Bb,                        K, &Bs[0][0],        t);
  stage_half(Ab + (size_t)128*K,        K, &As[0][128*64],   t);
  stage_half(Bb + (size_t)128*K,        K, &Bs[0][128*64],   t);
  stage_half(Ab + 64,                   K, &As[1][0],        t);
  stage_half(Bb + 64,                   K, &Bs[1][0],        t);
  asm volatile("s_waitcnt vmcnt(4)" ::: "memory");
  __builtin_amdgcn_s_barrier();

  for (int kt = 0; kt < NT; ++kt){
    const int bcur = kt & 1, bnxt = bcur ^ 1;
    const u16* Acur = &As[bcur][0];
    const u16* Bcur = &Bs[bcur][0];
    u16* AnH1 = &As[bnxt][128*64];     // t+1's A-half1
    u16* BnH1 = &Bs[bnxt][128*64];     // t+1's B-half1
    u16* AcH0 = &As[bcur][0];          // t+2's A-half0 (freed after P1)
    u16* BcH0 = &Bs[bcur][0];          // t+2's B-half0 (freed after P1)
    const int ko1 = (kt+1)*64, ko2 = (kt+2)*64;
    const bool s1 = (kt+1 < NT), s2 = (kt+2 < NT);

    // ---- P1 (mh0 x nh0): 12 ds_reads; stage A1(t+1)
    #pragma unroll
    for (int m=0;m<4;m++)
      #pragma unroll
      for (int ks=0;ks<2;ks++)
        af[m*2+ks] = frag_ld(Acur, wr*64 + m*16 + c, ks*4 + g);
    #pragma unroll
    for (int n=0;n<2;n++)
      #pragma unroll
      for (int ks=0;ks<2;ks++)
        bf0[n*2+ks] = frag_ld(Bcur, wc*32 + n*16 + c, ks*4 + g);
    if (s1) stage_half(Ab + (size_t)128*K + ko1, K, AnH1, t);
    __builtin_amdgcn_s_barrier();
    asm volatile("s_waitcnt lgkmcnt(0)" ::: "memory");
    __builtin_amdgcn_sched_barrier(0);
    __builtin_amdgcn_s_setprio(1);
    #pragma unroll
    for (int m=0;m<4;m++)
      #pragma unroll
      for (int n=0;n<2;n++)
        #pragma unroll
        for (int ks=0;ks<2;ks++)
          acc[m][n] = MFMA16(af[m*2+ks], bf0[n*2+ks], acc[m][n]);
    __builtin_amdgcn_s_setprio(0);
    __builtin_amdgcn_s_barrier();

    // ---- P2 (mh0 x nh1): 4 ds_reads (bf1); stage B1(t+1)
    #pragma unroll
    for (int n=0;n<2;n++)
      #pragma unroll
      for (int ks=0;ks<2;ks++)
        bf1[n*2+ks] = frag_ld(Bcur, 128 + wc*32 + n*16 + c, ks*4 + g);
    if (s1) stage_half(Bb + (size_t)128*K + ko1, K, BnH1, t);
    __builtin_amdgcn_s_barrier();
    asm volatile("s_waitcnt lgkmcnt(0)" ::: "memory");
    __builtin_amdgcn_sched_barrier(0);
    __builtin_amdgcn_s_setprio(1);
    #pragma unroll
    for (int m=0;m<4;m++)
      #pragma unroll
      for (int n=0;n<2;n++)
        #pragma unroll
        for (int ks=0;ks<2;ks++)
          acc[m][n+2] = MFMA16(af[m*2+ks], bf1[n*2+ks], acc[m][n+2]);
    __builtin_amdgcn_s_setprio(0);
    __builtin_amdgcn_s_barrier();

    // ---- P3 (mh1 x nh0): 8 ds_reads (af reload); stage A0(t+2) into bcur
    #pragma unroll
    for (int m=0;m<4;m++)
      #pragma unroll
      for (int ks=0;ks<2;ks++)
        af[m*2+ks] = frag_ld(Acur, 128 + wr*64 + m*16 + c, ks*4 + g);
    if (s2) stage_half(Ab + ko2, K, AcH0, t);
    __builtin_amdgcn_s_barrier();
    asm volatile("s_waitcnt lgkmcnt(0)" ::: "memory");
    __builtin_amdgcn_sched_barrier(0);
    __builtin_amdgcn_s_setprio(1);
    #pragma unroll
    for (int m=0;m<4;m++)
      #pragma unroll
      for (int n=0;n<2;n++)
        #pragma unroll
        for (int ks=0;ks<2;ks++)
          acc[m+4][n] = MFMA16(af[m*2+ks], bf0[n*2+ks], acc[m+4][n]);
    __builtin_amdgcn_s_setprio(0);
    __builtin_amdgcn_s_barrier();

    // ---- P4 (mh1 x nh1): 0 ds_reads; stage B0(t+2); tile-boundary vmcnt
    if (s2) stage_half(Bb + ko2, K, BcH0, t);
    if (kt >= NT-3) asm volatile("s_waitcnt vmcnt(0)" ::: "memory");
    else            asm volatile("s_waitcnt vmcnt(4)" ::: "memory");
    __builtin_amdgcn_s_barrier();
    __builtin_amdgcn_sched_barrier(0);
    __builtin_amdgcn_s_setprio(1);
    #pragma unroll
    for (int m=0;m<4;m++)
      #pragma unroll
      for (int n=0;n<2;n++)
        #pragma unroll
        for (int ks=0;ks<2;ks++)
          acc[m+4][n+2] = MFMA16(af[m*2+ks], bf1[n*2+ks], acc[m+4][n+2]);
    __builtin_amdgcn_s_setprio(0);
    __builtin_amdgcn_s_barrier();
  }

  // epilogue: QKV scatter (same proven mapping as 128^2 kernel)
  #pragma unroll
  for (int m=0;m<8;m++){
    int arow = (m<4) ? (wr*64 + m*16) : (128 + wr*64 + (m-4)*16);
    int growb = m0 + arow + g*4;
    #pragma unroll
    for (int n=0;n<4;n++){
      int bcol = (n<2) ? (wc*32 + n*16) : (128 + wc*32 + (n-2)*16);
      int gcol = n0 + bcol + c;
      float bv = bias[gcol];
      int which = gcol / EMB;           // 0=Q 1=K 2=V (uniform per 16-col frag)
      int e = gcol - which*EMB;
      int hh = e >> 6, d2 = e & 63;
      int bi = growb >> 11, sb = growb & 2047;
      size_t bh = (size_t)bi*NH + hh;
      if (which == 2){
        uint2 pv2;
        pv2.x = pk2(acc[m][n][0] + bv, acc[m][n][1] + bv);
        pv2.y = pk2(acc[m][n][2] + bv, acc[m][n][3] + bv);
        *(uint2*)(vT + (bh*HD + d2)*SEQ + sb) = pv2;
      } else {
        u16* dst = (which == 0) ? qb : kbf;
        float scl = (which == 0) ? QSCALE : 1.0f;
        #pragma unroll
        for (int r=0;r<4;r++)
          dst[(bh*SEQ + sb + r)*HD + d2] = f2bf((acc[m][n][r] + bv)*scl);
      }
    }
  }
}

// ------- 128^2 2-phase dbuf GEMM (kept for the output projection) ---------
template<int EPI>
__global__ __launch_bounds__(256) void gemm_bt_kernel(
    const u16* __restrict__ A, const u16* __restrict__ Bt, const float* __restrict__ bias,
    float* __restrict__ Cout, int Ntot, int K,
    u16* __restrict__ qb, u16* __restrict__ kbf, u16* __restrict__ vT)
{
  __shared__ u16 As[2][128*64];
  __shared__ u16 Bs[2][128*64];
  int t = threadIdx.x;
  int lane = t & 63, w = t >> 6;
  int wr = w >> 1, wc = w & 1;
  int g = lane >> 4, c = lane & 15;
  int m0 = blockIdx.y*128, n0 = blockIdx.x*128;
  const u16* Ab = A  + (size_t)m0*K;
  const u16* Bb = Bt + (size_t)n0*K;
  f32x4 acc[4][4] = {};
  int NT = K/64;
  stage_swz<4>(Ab, K, As[0], t);
  stage_swz<4>(Bb, K, Bs[0], t);
  for (int kt = 0; kt < NT; ++kt){
    int d = kt & 1;
    if (kt < NT-1){
      int k1 = (kt+1)*64;
      stage_swz<4>(Ab + k1, K, As[d^1], t);
      stage_swz<4>(Bb + k1, K, Bs[d^1], t);
      asm volatile("s_waitcnt vmcnt(8)" ::: "memory");
    } else {
      asm volatile("s_waitcnt vmcnt(0)" ::: "memory");
    }
    __builtin_amdgcn_s_barrier();
    __builtin_amdgcn_sched_barrier(0);
    #pragma unroll
    for (int kb2=0;kb2<2;kb2++){
      s8v af[4], bfr[4];
      #pragma unroll
      for (int m=0;m<4;m++) af[m]  = frag_ld(As[d], wr*64 + m*16 + c, kb2*4 + g);
      #pragma unroll
      for (int n=0;n<4;n++) bfr[n] = frag_ld(Bs[d], wc*64 + n*16 + c, kb2*4 + g);
      #pragma unroll
      for (int m=0;m<4;m++)
        #pragma unroll
        for (int n=0;n<4;n++)
          acc[m][n] = MFMA16(af[m], bfr[n], acc[m][n]);
    }
    asm volatile("s_waitcnt lgkmcnt(0)" ::: "memory");
    __builtin_amdgcn_s_barrier();
  }
  #pragma unroll
  for (int m=0;m<4;m++){
    int growb = m0 + wr*64 + m*16 + g*4;
    #pragma unroll
    for (int n=0;n<4;n++){
      int gcol = n0 + wc*64 + n*16 + c;
      float bv = bias[gcol];
      if (EPI == 1){
        #pragma unroll
        for (int r=0;r<4;r++)
          Cout[(size_t)(growb + r)*Ntot + gcol] = acc[m][n][r] + bv;
      } else {
        int which = gcol / EMB;
        int e = gcol - which*EMB;
        int hh = e >> 6, d2 = e & 63;
        int bi = growb >> 11, sb = growb & 2047;
        size_t bh = (size_t)bi*NH + hh;
        if (which == 2){
          uint2 pv2;
          pv2.x = pk2(acc[m][n][0] + bv, acc[m][n][1] + bv);
          pv2.y = pk2(acc[m][n][2] + bv, acc[m][n][3] + bv);
          *(uint2*)(vT + (bh*HD + d2)*SEQ + sb) = pv2;
        } else {
          u16* dst = (which == 0) ? qb : kbf;
          float scl = (which == 0) ? QSCALE : 1.0f;
          #pragma unroll
          for (int r=0;r<4;r++)
            dst[(bh*SEQ + sb + r)*HD + d2] = f2bf((acc[m][n][r] + bv)*scl);
        }
      }
    }
  }
}

// ------- causal flash attention: dbuf + counted vmcnt + O^T PV ------------
__global__ __launch_bounds__(256) void attn_kernel(
    const u16* __restrict__ qb, const u16* __restrict__ kbf, const u16* __restrict__ vT,
    u16* __restrict__ attn)
{
  __shared__ u16 Kls[2][64*64];
  __shared__ u16 Vls[2][64*64];
  __shared__ u16 Ps[4][1024];
  int bh = blockIdx.x;
  int b = bh / NH, h = bh - b*NH;
  int qt = 31 - blockIdx.y;
  int t = threadIdx.x, lane = t & 63, w = t >> 6;
  int g = lane >> 4, c = lane & 15;
  u16* pw = &Ps[w][0];
  const u16* Kb = kbf + (size_t)bh*SEQ*HD;
  const u16* Vb = vT  + (size_t)bh*HD*SEQ;

  int qwb = qt*64 + w*16;
  const u16* qrow = qb + ((size_t)bh*SEQ + qwb + c)*HD;
  s8v aq0 = *(const s8v*)(qrow + g*8);
  s8v aq1 = *(const s8v*)(qrow + 32 + g*8);
  f32x4 po[4] = {};
  float mrow = -1e30f, lrow = 0.f;
  int cswz = 2*(c & 7);

  stage_swz<2>(Kb, HD, Kls[0], t);
  stage_swz<2>(Vb, SEQ, Vls[0], t);

  for (int kt = 0; kt <= qt; ++kt){
    int cur = kt & 1;
    const u16* Ks = Kls[cur];
    const u16* Vs = Vls[cur];
    if (kt < qt){
      int k1 = (kt + 1)*64;
      stage_swz<2>(Kb + (size_t)k1*HD, HD,  Kls[cur^1], t);
      stage_swz<2>(Vb + k1,            SEQ, Vls[cur^1], t);
      asm volatile("s_waitcnt vmcnt(4)" ::: "memory");
    } else {
      asm volatile("s_waitcnt vmcnt(0)" ::: "memory");
    }
    __builtin_amdgcn_s_barrier();
    __builtin_amdgcn_sched_barrier(0);

    int k0 = kt*64;
    s8v vv[8];
    #pragma unroll
    for (int kb2=0;kb2<2;kb2++)
      #pragma unroll
      for (int dt=0;dt<4;dt++)
        vv[kb2*4+dt] = frag_ld(Vs, dt*16 + c, kb2*4 + g);
    f32x4 sc[4];
    __builtin_amdgcn_s_setprio(1);
    #pragma unroll
    for (int nt=0;nt<4;nt++){
      s8v k0f = frag_ld(Ks, nt*16 + c, g);
      s8v k1f = frag_ld(Ks, nt*16 + c, 4 + g);
      f32x4 z = {0.f,0.f,0.f,0.f};
      sc[nt] = MFMA16(k0f, aq0, z);
      sc[nt] = MFMA16(k1f, aq1, sc[nt]);
    }
    __builtin_amdgcn_s_setprio(0);
    if (kt == qt){
      #pragma unroll
      for (int nt=0;nt<4;nt++){
        int kg = k0 + nt*16 + g*4;
        #pragma unroll
        for (int r=0;r<4;r++)
          if (kg + r > qwb + c) sc[nt][r] = -1e30f;
      }
    }
    float mt = fmaxf(fmaxf(sc[0][0],sc[0][1]), fmaxf(sc[0][2],sc[0][3]));
    #pragma unroll
    for (int nt=1;nt<4;nt++)
      mt = fmaxf(mt, fmaxf(fmaxf(sc[nt][0],sc[nt][1]), fmaxf(sc[nt][2],sc[nt][3])));
    mt = fmaxf(mt, __shfl_xor(mt, 16));
    mt = fmaxf(mt, __shfl_xor(mt, 32));
    if (!__all(mt - mrow <= 8.0f)){
      float mn = fmaxf(mrow, mt);
      float alpha = exp2f(mrow - mn);
      mrow = mn;
      lrow *= alpha;
      #pragma unroll
      for (int dt=0;dt<4;dt++)
        #pragma unroll
        for (int r=0;r<4;r++)
          po[dt][r] *= alpha;
    }
    float rs = 0.f;
    #pragma unroll
    for (int nt=0;nt<4;nt++)
      #pragma unroll
      for (int r=0;r<4;r++){
        float pe = exp2f(sc[nt][r] - mrow);
        sc[nt][r] = pe;
        rs += pe;
      }
    rs += __shfl_xor(rs, 16);
    rs += __shfl_xor(rs, 32);
    lrow += rs;
    #pragma unroll
    for (int nt=0;nt<4;nt++){
      uint2 pk;
      pk.x = pk2(sc[nt][0], sc[nt][1]);
      pk.y = pk2(sc[nt][2], sc[nt][3]);
      *(uint2*)(pw + c*64 + ((nt*4 + g) ^ cswz)*4) = pk;
    }
    __builtin_amdgcn_s_setprio(1);
    #pragma unroll
    for (int kb2=0;kb2<2;kb2++){
      s8v pa = *(const s8v*)(pw + c*64 + ((kb2*8 + 2*g) ^ cswz)*4);
      #pragma unroll
      for (int dt=0;dt<4;dt++)
        po[dt] = MFMA16(vv[kb2*4+dt], pa, po[dt]);
    }
    __builtin_amdgcn_s_setprio(0);
    asm volatile("s_waitcnt lgkmcnt(0)" ::: "memory");
    __builtin_amdgcn_s_barrier();
  }
  float inv = 1.0f / lrow;
  const size_t orow = ((size_t)(b*SEQ + qwb + c))*EMB + h*HD;
  #pragma unroll
  for (int dt=0;dt<4;dt++){
    uint2 o;
    o.x = pk2(po[dt][0]*inv, po[dt][1]*inv);
    o.y = pk2(po[dt][2]*inv, po[dt][3]*inv);
    *(uint2*)(attn + orow + dt*16 + g*4) = o;
  }
}

extern "C" void kernel_launch(void* const* d_in, const int* in_sizes, int n_in,
                              void* d_out, int out_size, void* d_ws, size_t ws_size,
                              hipStream_t stream) {
  const float* hs    = (const float*)d_in[0];
  const float* qkv_w = (const float*)d_in[1];
  const float* qkv_b = (const float*)d_in[2];
  const float* out_w = (const float*)d_in[3];
  const float* out_b = (const float*)d_in[4];
  float* out = (float*)d_out;

  char* p = (char*)d_ws;
  u16* xb    = (u16*)p; p += (size_t)MT*EMB*2;
  u16* wqkvT = (u16*)p; p += (size_t)N3E*EMB*2;
  u16* woT   = (u16*)p; p += (size_t)EMB*EMB*2;
  u16* qbuf  = (u16*)p; p += (size_t)NB*NH*SEQ*HD*2;
  u16* kbuf  = (u16*)p; p += (size_t)NB*NH*SEQ*HD*2;
  u16* vTb   = (u16*)p; p += (size_t)NB*NH*SEQ*HD*2;
  u16* attnb = (u16*)p; p += (size_t)MT*EMB*2;

  prep_kernel<<<11520, 256, 0, stream>>>(hs, qkv_w, out_w, xb, wqkvT, woT);
  gemm256_qkv_kernel<<<240, 512, 0, stream>>>(
      xb, wqkvT, qkv_b, qbuf, kbuf, vTb);
  attn_kernel<<<dim3(40, 32), 256, 0, stream>>>(qbuf, kbuf, vTb, attnb);
  gemm_bt_kernel<1><<<dim3(EMB/128, MT/128), 256, 0, stream>>>(
      attnb, woT, out_b, out, EMB, EMB, nullptr, nullptr, nullptr);
}